// Round 1
// 274.297 us; speedup vs baseline: 1.0377x; 1.0377x over previous
//
#include <hip/hip_runtime.h>

typedef __attribute__((ext_vector_type(8))) short short8;
typedef __attribute__((ext_vector_type(4))) float f32x4;
typedef __attribute__((ext_vector_type(4))) unsigned short u16x4;

__device__ __forceinline__ unsigned short f2b(float f) {
  unsigned int u = __float_as_uint(f);
  u += 0x7fffu + ((u >> 16) & 1u);   // RNE
  return (unsigned short)(u >> 16);
}
__device__ __forceinline__ void glds16(const void* g, void* l) {
  __builtin_amdgcn_global_load_lds(
      (const __attribute__((address_space(1))) unsigned int*)g,
      (__attribute__((address_space(3))) unsigned int*)l, 16, 0, 0);
}

// ------------------------------------------------- fused cast: all 5 inputs -> bf16
__global__ __launch_bounds__(256) void cast_all(const float* __restrict__ x,
                                                const float* __restrict__ wq,
                                                const float* __restrict__ wk,
                                                const float* __restrict__ wv,
                                                const float* __restrict__ wo,
                                                unsigned short* __restrict__ dst) {
  const int i = blockIdx.x * 256 + threadIdx.x;   // < 4,718,592 (grid exact)
  const float* s;
  int off;
  if (i < 2097152)      { s = x;  off = i; }
  else if (i < 3145728) { s = wq; off = i - 2097152; }
  else if (i < 3407872) { s = wk; off = i - 3145728; }
  else if (i < 3670016) { s = wv; off = i - 3407872; }
  else                  { s = wo; off = i - 3670016; }
  f32x4 v = ((const f32x4*)s)[off];
  u16x4 o;
  o[0] = f2b(v[0]); o[1] = f2b(v[1]); o[2] = f2b(v[2]); o[3] = f2b(v[3]);
  ((u16x4*)dst)[i] = o;
}

// ------------------------------------------------------------------ 256x256 8-phase GEMM
// C = A * B^T, BM=BN=256, BK=64, 8 waves (2Mx4N), 512 threads, 128 KiB LDS.
// LDS per half-tile (128x64 bf16 = 16 KiB): [8][2] subtiles of 16x32 (1024 B), with
// st_16x32 XOR swizzle (within-subtile colbyte ^= (row&8)<<2) applied via PRE-SWIZZLED
// global source + linear global_load_lds dest, de-swizzled on ds_read (rule: both sides).
// Per K-tile: 4 phases, each {ds_read frag subtile; stage 1 half; barrier; lgkmcnt(0);
// setprio(1); 16 MFMA; setprio(0); barrier}; counted vmcnt(4) once per tile (phase 4).
// Staging order: A1(T+1)@P1, B1(T+1)@P2 (other dbuf, dead since T-1 P3/P2);
//                B0(T+2)@P3, A0(T+2)@P4 (own dbuf: B dead after P2, A after P3).
// mode=1 (qkv): B n-block read is PERMUTED (nb = bb&1 ? 4+(bb>>1) : bb>>1) so thread
// fragments ni=2j / 2j+1 hold rope partners (d, d+64) -> thread-local RoPE epilogue.
// mode=0: plain fp32 C.
__global__ __launch_bounds__(512, 2) void gemm256(
    const unsigned short* __restrict__ A, const unsigned short* __restrict__ B,
    const int K, const int mode,
    unsigned short* __restrict__ qb, unsigned short* __restrict__ kb,
    unsigned short* __restrict__ vtg, float* __restrict__ Cout, const int N) {
  extern __shared__ char smem[];   // [2 dbuf][A:2x16K | B:2x16K] = 131072 B
  const int tid = threadIdx.x;
  const int w = tid >> 6, lane = tid & 63;
  const int quad = lane >> 4, l15 = lane & 15;
  const int wm = w >> 2, wn = w & 3;
  const int m0 = blockIdx.x * 256, n0 = blockIdx.y * 256;
  const int nkt = K >> 6;

  // B n-block mapping (identity for mode 0; rope-pairing permutation for mode 1)
  int nb[4];
#pragma unroll
  for (int ni = 0; ni < 4; ++ni) {
    const int bbi = (wn & 1) * 4 + ni;
    nb[ni] = mode ? ((bbi & 1) ? 4 + (bbi >> 1) : (bbi >> 1)) : bbi;
  }

  // ds_read fragment byte offset within a subtile (swizzled)
  const int fragOff = l15 * 64 + ((quad * 16) ^ ((l15 & 8) << 2));
  char* const aWave = smem + wm * 16384;               // + dbuf*65536
  char* const bWave = smem + 32768 + (wn >> 1) * 16384;

  // staging: subtile s = j*8+w; lane l covers subtile bytes [l*16, l*16+16)
  //   -> row (s>>1)*16 + (l>>2), swizzled colbyte (l&3)*16 ^ ((l&32)?32:0)
  const int sr = lane >> 2;
  const int sc = ((lane & 3) * 8) ^ ((lane & 32) ? 16 : 0);   // bf16 col, pre-swizzled

  auto stageA = [&](int buf, int h, int kt) {
#pragma unroll
    for (int j = 0; j < 2; ++j) {
      const int s = j * 8 + w;
      glds16(A + (size_t)(m0 + h * 128 + (s >> 1) * 16 + sr) * K + kt * 64 + (s & 1) * 32 + sc,
             smem + buf * 65536 + h * 16384 + s * 1024);
    }
  };
  auto stageB = [&](int buf, int h, int kt) {
#pragma unroll
    for (int j = 0; j < 2; ++j) {
      const int s = j * 8 + w;
      glds16(B + (size_t)(n0 + h * 128 + (s >> 1) * 16 + sr) * K + kt * 64 + (s & 1) * 32 + sc,
             smem + buf * 65536 + 32768 + h * 16384 + s * 1024);
    }
  };

  f32x4 acc[8][4];
  const f32x4 fz = {0.f, 0.f, 0.f, 0.f};
#pragma unroll
  for (int i = 0; i < 8; ++i)
#pragma unroll
    for (int j = 0; j < 4; ++j) acc[i][j] = fz;

  // prologue: tile0 fully + tile1 {B0, A0}; issue order defines vmcnt semantics
  stageB(0, 0, 0); stageA(0, 0, 0); stageA(0, 1, 0); stageB(0, 1, 0);
  stageB(1, 0, 1); stageA(1, 0, 1);
  asm volatile("s_waitcnt vmcnt(4)" ::: "memory");   // tile0 complete; 2 halves in flight
  __builtin_amdgcn_s_barrier();

  short8 af[4][2], blo[2][2], bhi[2][2];

#define MFMA_Q(MOFF, NOFF, BF)                                                   \
  _Pragma("unroll") for (int mi = 0; mi < 4; ++mi)                               \
  _Pragma("unroll") for (int ni = 0; ni < 2; ++ni)                               \
  _Pragma("unroll") for (int kk = 0; kk < 2; ++kk)                               \
      acc[(MOFF) + mi][(NOFF) + ni] = __builtin_amdgcn_mfma_f32_16x16x32_bf16(   \
          af[mi][kk], BF[ni][kk], acc[(MOFF) + mi][(NOFF) + ni], 0, 0, 0);

  for (int T = 0; T < nkt; ++T) {
    const int c = T & 1;
    char* const ab = aWave + c * 65536;
    char* const bp = bWave + c * 65536;

    // ---- P1: read A-lo (8) + B-lo (4); stage A1(T+1); MFMA (m-lo, n-lo)
#pragma unroll
    for (int mi = 0; mi < 4; ++mi)
#pragma unroll
      for (int kk = 0; kk < 2; ++kk)
        af[mi][kk] = *(const short8*)(ab + (mi * 2 + kk) * 1024 + fragOff);
#pragma unroll
    for (int ni = 0; ni < 2; ++ni)
#pragma unroll
      for (int kk = 0; kk < 2; ++kk)
        blo[ni][kk] = *(const short8*)(bp + (nb[ni] * 2 + kk) * 1024 + fragOff);
    if (T + 1 < nkt) stageA(c ^ 1, 1, T + 1);
    __builtin_amdgcn_s_barrier();
    asm volatile("s_waitcnt lgkmcnt(0)" ::: "memory");
    __builtin_amdgcn_s_setprio(1);
    MFMA_Q(0, 0, blo)
    __builtin_amdgcn_s_setprio(0);
    __builtin_amdgcn_s_barrier();

    // ---- P2: read B-hi (4); stage B1(T+1); MFMA (m-lo, n-hi)
#pragma unroll
    for (int ni = 0; ni < 2; ++ni)
#pragma unroll
      for (int kk = 0; kk < 2; ++kk)
        bhi[ni][kk] = *(const short8*)(bp + (nb[ni + 2] * 2 + kk) * 1024 + fragOff);
    if (T + 1 < nkt) stageB(c ^ 1, 1, T + 1);
    __builtin_amdgcn_s_barrier();
    asm volatile("s_waitcnt lgkmcnt(0)" ::: "memory");
    __builtin_amdgcn_s_setprio(1);
    MFMA_Q(0, 2, bhi)
    __builtin_amdgcn_s_setprio(0);
    __builtin_amdgcn_s_barrier();

    // ---- P3: read A-hi (8, overwrite af); stage B0(T+2); MFMA (m-hi, n-hi)
#pragma unroll
    for (int mi = 0; mi < 4; ++mi)
#pragma unroll
      for (int kk = 0; kk < 2; ++kk)
        af[mi][kk] = *(const short8*)(ab + ((mi + 4) * 2 + kk) * 1024 + fragOff);
    if (T + 2 < nkt) stageB(c, 0, T + 2);
    __builtin_amdgcn_s_barrier();
    asm volatile("s_waitcnt lgkmcnt(0)" ::: "memory");
    __builtin_amdgcn_s_setprio(1);
    MFMA_Q(4, 2, bhi)
    __builtin_amdgcn_s_setprio(0);
    __builtin_amdgcn_s_barrier();

    // ---- P4: stage A0(T+2); MFMA (m-hi, n-lo); counted vmcnt; barrier
    if (T + 2 < nkt) stageA(c, 0, T + 2);
    __builtin_amdgcn_s_barrier();
    __builtin_amdgcn_s_setprio(1);
    MFMA_Q(4, 0, blo)
    __builtin_amdgcn_s_setprio(0);
    if (T + 2 < nkt) { asm volatile("s_waitcnt vmcnt(4)" ::: "memory"); }
    else             { asm volatile("s_waitcnt vmcnt(0)" ::: "memory"); }  // tail drain
    __builtin_amdgcn_s_barrier();
  }
#undef MFMA_Q

  // ------------------------------------------------------------------ epilogues
  if (mode == 0) {
    const int colBase = n0 + wn * 64;
#pragma unroll
    for (int mi = 0; mi < 8; ++mi) {
      const int row = m0 + wm * 128 + mi * 16 + quad * 4;
#pragma unroll
      for (int ni = 0; ni < 4; ++ni) {
        const int col = colBase + ni * 16 + l15;
#pragma unroll
        for (int r = 0; r < 4; ++r)
          Cout[(size_t)(row + r) * N + col] = acc[mi][ni][r];
      }
    }
    return;
  }

  const int y = blockIdx.y;            // 0-7: Q heads 2y,2y+1 | 8-9: K | 10-11: V
  const int tb0 = m0 + wm * 128;
  if (y >= 10) {
    // ---- V: store transposed into vtg[g][d][t]; d un-permutes via nb[]
    const int g = (y - 10) * 2 + (wn >> 1);
#pragma unroll
    for (int mi = 0; mi < 8; ++mi) {
      const int tb = tb0 + mi * 16 + quad * 4;
#pragma unroll
      for (int ni = 0; ni < 4; ++ni) {
        const int d = nb[ni] * 16 + l15;
        u16x4 o;
#pragma unroll
        for (int r = 0; r < 4; ++r) o[r] = f2b(acc[mi][ni][r]);
        *(u16x4*)(vtg + (size_t)(g * 128 + d) * 4096 + tb) = o;
      }
    }
  } else {
    // ---- Q/K: thread-local RoPE; acc[mi][2j] holds d=i<64, acc[mi][2j+1] holds d=i+64
    unsigned short* dst;
    int stride, hoff;
    if (y < 8) { dst = qb; stride = 2048; hoff = (y * 2 + (wn >> 1)) * 128; }
    else       { dst = kb; stride = 512;  hoff = ((y - 8) * 2 + (wn >> 1)) * 128; }
    const float c2 = 0.20762050593045889f;   // log2(10000)/64
    const float inv2pi = 0.15915494309189535f;
#pragma unroll
    for (int j = 0; j < 2; ++j) {
      const int i = ((wn & 1) * 2 + j) * 16 + l15;            // rope dim, < 64
      const float inv_rev = exp2f(-(float)i * c2) * inv2pi;   // freq in revolutions
#pragma unroll
      for (int mi = 0; mi < 8; ++mi) {
#pragma unroll
        for (int r = 0; r < 4; ++r) {
          const int t = tb0 + mi * 16 + quad * 4 + r;
          float rev = (float)t * inv_rev;
          rev -= floorf(rev);                    // [0,1) for HW v_sin/v_cos
          const float sn = __builtin_amdgcn_sinf(rev);
          const float cs = __builtin_amdgcn_cosf(rev);
          const float x1 = acc[mi][2 * j][r], x2 = acc[mi][2 * j + 1][r];
          unsigned short* p = dst + (size_t)t * stride + hoff + i;
          p[0]  = f2b(x1 * cs - x2 * sn);
          p[64] = f2b(x1 * sn + x2 * cs);
        }
      }
    }
  }
}

// ------------------------------------------------------------ windowed GQA attention
// Block: 8 waves, 64 queries, one kv group. wave w: head g*4+(w&3), query-half w>>2.
__global__ __launch_bounds__(512) void attn_fwd(const unsigned short* __restrict__ qp,
                                                const unsigned short* __restrict__ kp,
                                                const unsigned short* __restrict__ vtg,
                                                unsigned short* __restrict__ op) {
  __shared__ unsigned short Ks[2][4][1024];   // [buf][kb][key*32+d']
  __shared__ unsigned short Vt[2][4096];      // [buf][d*32+key]
  const int tid = threadIdx.x;
  const int w = tid >> 6, lane = tid & 63;
  const int quad = lane >> 4, l15 = lane & 15;
  const int t0 = blockIdx.x * 64;
  const int g = blockIdx.y;
  const int h = g * 4 + (w & 3);
  const int t0w = t0 + (w >> 2) * 32;         // this wave's 32-query base
  const f32x4 fzero = {0.f, 0.f, 0.f, 0.f};
  const float scale = 0.088388347648318447f;  // 1/sqrt(128)
  const float NEG_INF = -__builtin_inff();

  short8 qf[4][2];
#pragma unroll
  for (int qt = 0; qt < 2; qt++) {
    const unsigned short* qrow = qp + (size_t)(t0w + qt * 16 + l15) * 2048 + h * 128 + quad * 8;
#pragma unroll
    for (int kb = 0; kb < 4; kb++) qf[kb][qt] = *(const short8*)(qrow + kb * 32);
  }

  f32x4 oacc[8][2];
#pragma unroll
  for (int db = 0; db < 8; db++) { oacc[db][0] = fzero; oacc[db][1] = fzero; }
  float Mrow[2] = {-1.0e30f, -1.0e30f}, Lrow[2] = {0.f, 0.f};

  const int s_begin = (t0 >= 512) ? (t0 - 512) : 0;
  const int nch = ((t0 + 63 - s_begin) >> 5) + 1;

  const int r4 = lane >> 2, c4 = lane & 3;
#define ATTN_STAGE(s0_, b_)                                                              \
  {                                                                                      \
    const int s0v = (s0_);                                                               \
    if (w < 4) {                                                                         \
      _Pragma("unroll")                                                                  \
      for (int p = 0; p < 2; p++)                                                        \
        glds16(kp + (size_t)(s0v + p * 16 + r4) * 512 + g * 128 + w * 32 + c4 * 8,       \
               &Ks[b_][w][p * 512]);                                                     \
    } else {                                                                             \
      const int wv = w - 4;                                                              \
      _Pragma("unroll")                                                                  \
      for (int p = 0; p < 2; p++)                                                        \
        glds16(vtg + (size_t)(g * 128 + wv * 32 + p * 16 + r4) * 4096 + s0v + c4 * 8,    \
               &Vt[b_][wv * 1024 + p * 512]);                                            \
    }                                                                                    \
  }

  ATTN_STAGE(s_begin, 0);

  for (int c = 0; c < nch; ++c) {
    const int s0 = s_begin + c * 32;
    const int b = c & 1;
    __syncthreads();                       // drain glds for chunk c (uniform)
    if (c + 1 < nch) ATTN_STAGE(s_begin + (c + 1) * 32, (c + 1) & 1);

    if (s0 + 31 >= t0w - 512 && s0 <= t0w + 31) {
      // ---- S^T = K * Q^T, permuted key rows
      f32x4 sacc[2][2];
      sacc[0][0] = fzero; sacc[0][1] = fzero; sacc[1][0] = fzero; sacc[1][1] = fzero;
      const int permBase = ((l15 >> 2) << 3) + (l15 & 3);   // + 4*kt
#pragma unroll
      for (int kb = 0; kb < 4; kb++) {
        short8 af0 = *(const short8*)&Ks[b][kb][(permBase + 0) * 32 + quad * 8];
        short8 af1 = *(const short8*)&Ks[b][kb][(permBase + 4) * 32 + quad * 8];
        sacc[0][0] = __builtin_amdgcn_mfma_f32_16x16x32_bf16(af0, qf[kb][0], sacc[0][0], 0, 0, 0);
        sacc[0][1] = __builtin_amdgcn_mfma_f32_16x16x32_bf16(af0, qf[kb][1], sacc[0][1], 0, 0, 0);
        sacc[1][0] = __builtin_amdgcn_mfma_f32_16x16x32_bf16(af1, qf[kb][0], sacc[1][0], 0, 0, 0);
        sacc[1][1] = __builtin_amdgcn_mfma_f32_16x16x32_bf16(af1, qf[kb][1], sacc[1][1], 0, 0, 0);
      }

      // ---- masked online softmax; key for (kt,r) = s0 + quad*8 + kt*4 + r
      short8 pb[2];
      float alpha[2];
#pragma unroll
      for (int qt = 0; qt < 2; qt++) {
        const int tq = t0w + qt * 16 + l15;
        float vals[8];
        float cmax = NEG_INF;
#pragma unroll
        for (int kt = 0; kt < 2; kt++)
#pragma unroll
          for (int r = 0; r < 4; r++) {
            const int s = s0 + quad * 8 + kt * 4 + r;
            const bool ok = (unsigned)(tq - s) <= 512u;
            const float v = ok ? sacc[kt][qt][r] * scale : NEG_INF;
            vals[kt * 4 + r] = v;
            cmax = fmaxf(cmax, v);
          }
        cmax = fmaxf(cmax, __shfl_xor(cmax, 16));
        cmax = fmaxf(cmax, __shfl_xor(cmax, 32));
        const float Mnew = fmaxf(Mrow[qt], cmax);
        alpha[qt] = __expf(Mrow[qt] - Mnew);
        Mrow[qt] = Mnew;
        float csum = 0.f;
#pragma unroll
        for (int j = 0; j < 8; j++) {
          const float p = __expf(vals[j] - Mnew);
          csum += p;
          pb[qt][j] = (short)f2b(p);
        }
        csum += __shfl_xor(csum, 16);
        csum += __shfl_xor(csum, 32);
        Lrow[qt] = Lrow[qt] * alpha[qt] + csum;
      }

      // ---- O^T += V^T * P^T
#pragma unroll
      for (int db = 0; db < 8; db++) {
        short8 vf = *(const short8*)&Vt[b][(db * 16 + l15) * 32 + quad * 8];
#pragma unroll
        for (int qt = 0; qt < 2; qt++) {
          oacc[db][qt][0] *= alpha[qt]; oacc[db][qt][1] *= alpha[qt];
          oacc[db][qt][2] *= alpha[qt]; oacc[db][qt][3] *= alpha[qt];
          oacc[db][qt] = __builtin_amdgcn_mfma_f32_16x16x32_bf16(vf, pb[qt], oacc[db][qt], 0, 0, 0);
        }
      }
    }
  }
#undef ATTN_STAGE

#pragma unroll
  for (int qt = 0; qt < 2; qt++) {
    const float invL = 1.f / Lrow[qt];
    unsigned short* orow = op + (size_t)(t0w + qt * 16 + l15) * 2048 + h * 128;
#pragma unroll
    for (int db = 0; db < 8; db++) {
      u16x4 o;
#pragma unroll
      for (int r = 0; r < 4; r++) o[r] = f2b(oacc[db][qt][r] * invL);
      *(u16x4*)(orow + db * 16 + quad * 4) = o;
    }
  }
}

// ---------------------------------------------------------------- launch
extern "C" void kernel_launch(void* const* d_in, const int* in_sizes, int n_in,
                              void* d_out, int out_size, void* d_ws, size_t ws_size,
                              hipStream_t stream) {
  const float* x  = (const float*)d_in[0];
  const float* wq = (const float*)d_in[1];
  const float* wk = (const float*)d_in[2];
  const float* wv = (const float*)d_in[3];
  const float* wo = (const float*)d_in[4];
  float* out = (float*)d_out;
  char* ws = (char*)d_ws;

  // workspace map (~63 MB); attnb aliases xb (dead after gemm256 qkv)
  unsigned short* xb    = (unsigned short*)(ws + 0);           // 16,777,216 B
  unsigned short* wqkv  = (unsigned short*)(ws + 16777216);    // 12,582,912 B
  unsigned short* wob   = (unsigned short*)(ws + 29360128);    //  8,388,608 B
  unsigned short* qb    = (unsigned short*)(ws + 37748736);    // 16,777,216 B
  unsigned short* kbuf  = (unsigned short*)(ws + 54525952);    //  4,194,304 B
  unsigned short* vtg   = (unsigned short*)(ws + 58720256);    //  4,194,304 B
  unsigned short* attnb = xb;

  static bool attr_done = false;
  if (!attr_done) {   // allow 128 KiB dynamic LDS (host-side, not stream-ordered)
    hipFuncSetAttribute(reinterpret_cast<const void*>(gemm256),
                        hipFuncAttributeMaxDynamicSharedMemorySize, 131072);
    attr_done = true;
  }

  cast_all<<<18432, 256, 0, stream>>>(x, wq, wk, wv, wo, (unsigned short*)ws);

  // qkv proj + fused RoPE + fused V-transpose (256^2 8-phase; N=3072 -> 12 y-tiles)
  gemm256<<<dim3(16, 12), 512, 131072, stream>>>(xb, wqkv, 2048, 1,
                                                 qb, kbuf, vtg, nullptr, 0);

  attn_fwd<<<dim3(64, 4), 512, 0, stream>>>(qb, kbuf, vtg, attnb);

  // out = attn @ wo^T  (4096 x 2048, K=2048), fp32 out (256^2 8-phase)
  gemm256<<<dim3(16, 8), 512, 131072, stream>>>(attnb, wob, 2048, 0,
                                                nullptr, nullptr, nullptr, out, 2048);
}

// Round 3
// 261.839 us; speedup vs baseline: 1.0871x; 1.0476x over previous
//
#include <hip/hip_runtime.h>

typedef __attribute__((ext_vector_type(8))) short short8;
typedef __attribute__((ext_vector_type(4))) float f32x4;
typedef __attribute__((ext_vector_type(4))) unsigned short u16x4;

__device__ __forceinline__ unsigned short f2b(float f) {
  unsigned int u = __float_as_uint(f);
  u += 0x7fffu + ((u >> 16) & 1u);   // RNE
  return (unsigned short)(u >> 16);
}
__device__ __forceinline__ void glds16(const void* g, void* l) {
  __builtin_amdgcn_global_load_lds(
      (const __attribute__((address_space(1))) unsigned int*)g,
      (__attribute__((address_space(3))) unsigned int*)l, 16, 0, 0);
}

// ------------------------------------------------- fused cast: all 5 inputs -> bf16
__global__ __launch_bounds__(256) void cast_all(const float* __restrict__ x,
                                                const float* __restrict__ wq,
                                                const float* __restrict__ wk,
                                                const float* __restrict__ wv,
                                                const float* __restrict__ wo,
                                                unsigned short* __restrict__ dst) {
  const int i = blockIdx.x * 256 + threadIdx.x;   // < 4,718,592 (grid exact)
  const float* s;
  int off;
  if (i < 2097152)      { s = x;  off = i; }
  else if (i < 3145728) { s = wq; off = i - 2097152; }
  else if (i < 3407872) { s = wk; off = i - 3145728; }
  else if (i < 3670016) { s = wv; off = i - 3407872; }
  else                  { s = wo; off = i - 3670016; }
  f32x4 v = ((const f32x4*)s)[off];
  u16x4 o;
  o[0] = f2b(v[0]); o[1] = f2b(v[1]); o[2] = f2b(v[2]); o[3] = f2b(v[3]);
  ((u16x4*)dst)[i] = o;
}

// ------------------------------------------------------------------ 256x256 8-phase GEMM
// C = A * B^T, BM=BN=256, BK=64 (K=2048 hardcoded, 32 K-tiles), 8 waves (2Mx4N),
// 512 threads, 128 KiB LDS (2 dbuf x [A 32K | B 32K]).
// LDS: [8][2] subtiles of 16x32 bf16 (1024 B) per 128-row half; st_16x32 XOR swizzle
// via pre-swizzled global source + linear glds dest; de-swizzled on ds_read.
//
// READ-AHEAD schedule: phase i+1's fragment reads issue AFTER phase i's MFMA, so the
// LDS-read latency drains under the next phase's stage/barrier instead of serializing.
//   P1:                      | BAR | MFMA Q1(af=Alo,blo) | read bhi<-Bhi(T) | BAR
//   P2: stage A-j0(T+2) x2   | BAR | MFMA Q2(af,bhi)     | read af<-Ahi(T)  | BAR
//   P3: stage B full(T+2) x4 | BAR | MFMA Q3(af,bhi)     |                  | BAR
//   P4: stage A-j1(T+2) x2   | BAR | MFMA Q4(af,blo) | vmcnt(8) | read af,blo of T+1 | BAR
// Region-lifetime proof (race fix vs r2): in buf c, Alo subtiles free after P1-end BAR,
// B after P2-end (bhi retire), Ahi (j1) after P3-end -> stages above are each one
// barrier past their region's last read retirement. A-stage is SPLIT by j (j0@P2,
// j1@P4); B cannot split (mode-1 nb permutation interleaves blo/bhi across j) -> full
// B@P3. All 8 glds/tile target buf c in tile order -> vmcnt(8)@P4 drains tile T+1
// exactly (induction from 16-issue/vmcnt(8) prologue). Tail: stage K-index clamped to
// 31 (identical-byte rewrites, WAR-benign, uniform counts). Every s_barrier is fenced
// with asm memory clobbers so glds can't be compiler-hoisted into the prior phase.
// mode=1 (qkv): B n-block read permuted (nb) so ni=2j/2j+1 hold rope partners (d,d+64)
// -> thread-local RoPE epilogue. mode=0: plain fp32 C.
__global__ __launch_bounds__(512, 2) void gemm256(
    const unsigned short* __restrict__ A, const unsigned short* __restrict__ B,
    const int Karg, const int mode,
    unsigned short* __restrict__ qb, unsigned short* __restrict__ kb,
    unsigned short* __restrict__ vtg, float* __restrict__ Cout, const int Narg) {
  extern __shared__ char smem[];   // [2 dbuf][A:2x16K | B:2x16K] = 131072 B
  const int tid = threadIdx.x;
  const int w = tid >> 6, lane = tid & 63;
  const int quad = lane >> 4, l15 = lane & 15;
  const int wm = w >> 2, wn = w & 3;
  const int m0 = blockIdx.x * 256, n0 = blockIdx.y * 256;

  // B n-block mapping (identity for mode 0; rope-pairing permutation for mode 1)
  int nb[4];
#pragma unroll
  for (int ni = 0; ni < 4; ++ni) {
    const int bbi = (wn & 1) * 4 + ni;
    nb[ni] = mode ? ((bbi & 1) ? 4 + (bbi >> 1) : (bbi >> 1)) : bbi;
  }

  // ds_read fragment byte offset within a subtile (swizzled)
  const int fragOff = l15 * 64 + ((quad * 16) ^ ((l15 & 8) << 2));
  char* const aWave = smem + wm * 16384;               // + dbuf*65536
  char* const bWave = smem + 32768 + (wn >> 1) * 16384;

  // staging: subtile s = jj*8+w; lane l covers subtile bytes [l*16, l*16+16)
  const int sr = lane >> 2;
  const int sc = ((lane & 3) * 8) ^ ((lane & 32) ? 16 : 0);   // bf16 col, pre-swizzled
  const unsigned short* const Abase = A + (size_t)(m0 + (w >> 1) * 16 + sr) * 2048 + (w & 1) * 32 + sc;
  const unsigned short* const Bbase = B + (size_t)(n0 + (w >> 1) * 16 + sr) * 2048 + (w & 1) * 32 + sc;

#define BARF()                            \
  asm volatile("" ::: "memory");          \
  __builtin_amdgcn_s_barrier();           \
  asm volatile("" ::: "memory");

#define STAGE_AJ(h, tt, jj)                                                              \
  {                                                                                      \
    const int t_ = ((tt) < 32) ? (tt) : 31;                                              \
    glds16(Abase + (size_t)(h) * (128 * 2048) + (jj) * (64 * 2048) + (size_t)t_ * 64,    \
           smem + (t_ & 1) * 65536 + (h) * 16384 + (jj) * 8192 + w * 1024);              \
  }
#define STAGE_B2(h, tt)                                                                  \
  {                                                                                      \
    const int t_ = ((tt) < 32) ? (tt) : 31;                                              \
    char* const d_ = smem + (t_ & 1) * 65536 + 32768 + (h) * 16384 + w * 1024;           \
    glds16(Bbase + (size_t)(h) * (128 * 2048) + (size_t)t_ * 64, d_);                    \
    glds16(Bbase + (size_t)(h) * (128 * 2048) + (64 * 2048) + (size_t)t_ * 64, d_ + 8192); \
  }
#define RD_A(dst, c, MI0)                                                                \
  _Pragma("unroll") for (int mi = 0; mi < 4; ++mi)                                       \
  _Pragma("unroll") for (int kk = 0; kk < 2; ++kk)                                       \
      dst[mi][kk] = *(const short8*)(aWave + (c) * 65536 + (((MI0) + mi) * 2 + kk) * 1024 + fragOff);
#define RD_B(dst, c, NI0)                                                                \
  _Pragma("unroll") for (int ni = 0; ni < 2; ++ni)                                       \
  _Pragma("unroll") for (int kk = 0; kk < 2; ++kk)                                       \
      dst[ni][kk] = *(const short8*)(bWave + (c) * 65536 + (nb[(NI0) + ni] * 2 + kk) * 1024 + fragOff);

  f32x4 acc[8][4];
  const f32x4 fz = {0.f, 0.f, 0.f, 0.f};
#pragma unroll
  for (int i = 0; i < 8; ++i)
#pragma unroll
    for (int j = 0; j < 4; ++j) acc[i][j] = fz;

  short8 af[4][2], blo[2][2], bhi[2][2];

#define MFMA_Q(MOFF, NOFF, BF)                                                   \
  _Pragma("unroll") for (int mi = 0; mi < 4; ++mi)                               \
  _Pragma("unroll") for (int ni = 0; ni < 2; ++ni)                               \
  _Pragma("unroll") for (int kk = 0; kk < 2; ++kk)                               \
      acc[(MOFF) + mi][(NOFF) + ni] = __builtin_amdgcn_mfma_f32_16x16x32_bf16(   \
          af[mi][kk], BF[ni][kk], acc[(MOFF) + mi][(NOFF) + ni], 0, 0, 0);

  // prologue: tile0 (8 glds) then tile1 (8 glds), each in steady-state unit order
  STAGE_AJ(0, 0, 0) STAGE_AJ(1, 0, 0) STAGE_B2(0, 0) STAGE_B2(1, 0) STAGE_AJ(0, 0, 1) STAGE_AJ(1, 0, 1)
  STAGE_AJ(0, 1, 0) STAGE_AJ(1, 1, 0) STAGE_B2(0, 1) STAGE_B2(1, 1) STAGE_AJ(0, 1, 1) STAGE_AJ(1, 1, 1)
  asm volatile("s_waitcnt vmcnt(8)" ::: "memory");   // tile0 resident; tile1 in flight
  __builtin_amdgcn_s_barrier();
  asm volatile("" ::: "memory");
  RD_A(af, 0, 0)    // Alo(0)
  RD_B(blo, 0, 0)   // Blo(0)

#define HALF(c, tt)                                                                  \
  /* P1 */                                                                           \
  BARF()                                                                             \
  __builtin_amdgcn_s_setprio(1); MFMA_Q(0, 0, blo) __builtin_amdgcn_s_setprio(0);    \
  RD_B(bhi, (c), 2)                                                                  \
  BARF()                                                                             \
  /* P2 */ STAGE_AJ(0, (tt) + 2, 0) STAGE_AJ(1, (tt) + 2, 0)                         \
  BARF()                                                                             \
  __builtin_amdgcn_s_setprio(1); MFMA_Q(0, 2, bhi) __builtin_amdgcn_s_setprio(0);    \
  RD_A(af, (c), 4)                                                                   \
  BARF()                                                                             \
  /* P3 */ STAGE_B2(0, (tt) + 2) STAGE_B2(1, (tt) + 2)                               \
  BARF()                                                                             \
  __builtin_amdgcn_s_setprio(1); MFMA_Q(4, 2, bhi) __builtin_amdgcn_s_setprio(0);    \
  BARF()                                                                             \
  /* P4 */ STAGE_AJ(0, (tt) + 2, 1) STAGE_AJ(1, (tt) + 2, 1)                         \
  BARF()                                                                             \
  __builtin_amdgcn_s_setprio(1); MFMA_Q(4, 0, blo) __builtin_amdgcn_s_setprio(0);    \
  asm volatile("s_waitcnt vmcnt(8)" ::: "memory");                                   \
  RD_A(af, (c) ^ 1, 0)                                                               \
  RD_B(blo, (c) ^ 1, 0)

#pragma unroll 1
  for (int T = 0; T < 32; T += 2) {
    HALF(0, T)
    HALF(1, T + 1)
  }
  asm volatile("s_waitcnt vmcnt(0)" ::: "memory");   // drain clamped tail rewrites
#undef HALF
#undef MFMA_Q
#undef RD_A
#undef RD_B
#undef STAGE_AJ
#undef STAGE_B2
#undef BARF

  // ------------------------------------------------------------------ epilogues
  if (mode == 0) {
    const int colBase = n0 + wn * 64;
#pragma unroll
    for (int mi = 0; mi < 8; ++mi) {
      const int row = m0 + wm * 128 + mi * 16 + quad * 4;
#pragma unroll
      for (int ni = 0; ni < 4; ++ni) {
        const int col = colBase + ni * 16 + l15;
#pragma unroll
        for (int r = 0; r < 4; ++r)
          Cout[(size_t)(row + r) * 2048 + col] = acc[mi][ni][r];
      }
    }
    return;
  }

  const int y = blockIdx.y;            // 0-7: Q heads 2y,2y+1 | 8-9: K | 10-11: V
  const int tb0 = m0 + wm * 128;
  if (y >= 10) {
    // ---- V: store transposed into vtg[g][d][t]; d un-permutes via nb[]
    const int g = (y - 10) * 2 + (wn >> 1);
#pragma unroll
    for (int mi = 0; mi < 8; ++mi) {
      const int tb = tb0 + mi * 16 + quad * 4;
#pragma unroll
      for (int ni = 0; ni < 4; ++ni) {
        const int d = nb[ni] * 16 + l15;
        u16x4 o;
#pragma unroll
        for (int r = 0; r < 4; ++r) o[r] = f2b(acc[mi][ni][r]);
        *(u16x4*)(vtg + (size_t)(g * 128 + d) * 4096 + tb) = o;
      }
    }
  } else {
    // ---- Q/K: thread-local RoPE; acc[mi][2j] holds d=i<64, acc[mi][2j+1] holds d=i+64
    unsigned short* dst;
    int stride, hoff;
    if (y < 8) { dst = qb; stride = 2048; hoff = (y * 2 + (wn >> 1)) * 128; }
    else       { dst = kb; stride = 512;  hoff = ((y - 8) * 2 + (wn >> 1)) * 128; }
    const float c2 = 0.20762050593045889f;   // log2(10000)/64
    const float inv2pi = 0.15915494309189535f;
#pragma unroll
    for (int j = 0; j < 2; ++j) {
      const int i = ((wn & 1) * 2 + j) * 16 + l15;            // rope dim, < 64
      const float inv_rev = exp2f(-(float)i * c2) * inv2pi;   // freq in revolutions
#pragma unroll
      for (int mi = 0; mi < 8; ++mi) {
#pragma unroll
        for (int r = 0; r < 4; ++r) {
          const int t = tb0 + mi * 16 + quad * 4 + r;
          float rev = (float)t * inv_rev;
          rev -= floorf(rev);                    // [0,1) for HW v_sin/v_cos
          const float sn = __builtin_amdgcn_sinf(rev);
          const float cs = __builtin_amdgcn_cosf(rev);
          const float x1 = acc[mi][2 * j][r], x2 = acc[mi][2 * j + 1][r];
          unsigned short* p = dst + (size_t)t * stride + hoff + i;
          p[0]  = f2b(x1 * cs - x2 * sn);
          p[64] = f2b(x1 * sn + x2 * cs);
        }
      }
    }
  }
}

// ------------------------------------------------------------ windowed GQA attention
// Block: 8 waves, 64 queries, one kv group. wave w: head g*4+(w&3), query-half w>>2.
__global__ __launch_bounds__(512) void attn_fwd(const unsigned short* __restrict__ qp,
                                                const unsigned short* __restrict__ kp,
                                                const unsigned short* __restrict__ vtg,
                                                unsigned short* __restrict__ op) {
  __shared__ unsigned short Ks[2][4][1024];   // [buf][kb][key*32+d']
  __shared__ unsigned short Vt[2][4096];      // [buf][d*32+key]
  const int tid = threadIdx.x;
  const int w = tid >> 6, lane = tid & 63;
  const int quad = lane >> 4, l15 = lane & 15;
  const int t0 = blockIdx.x * 64;
  const int g = blockIdx.y;
  const int h = g * 4 + (w & 3);
  const int t0w = t0 + (w >> 2) * 32;         // this wave's 32-query base
  const f32x4 fzero = {0.f, 0.f, 0.f, 0.f};
  const float scale = 0.088388347648318447f;  // 1/sqrt(128)
  const float NEG_INF = -__builtin_inff();

  short8 qf[4][2];
#pragma unroll
  for (int qt = 0; qt < 2; qt++) {
    const unsigned short* qrow = qp + (size_t)(t0w + qt * 16 + l15) * 2048 + h * 128 + quad * 8;
#pragma unroll
    for (int kb = 0; kb < 4; kb++) qf[kb][qt] = *(const short8*)(qrow + kb * 32);
  }

  f32x4 oacc[8][2];
#pragma unroll
  for (int db = 0; db < 8; db++) { oacc[db][0] = fzero; oacc[db][1] = fzero; }
  float Mrow[2] = {-1.0e30f, -1.0e30f}, Lrow[2] = {0.f, 0.f};

  const int s_begin = (t0 >= 512) ? (t0 - 512) : 0;
  const int nch = ((t0 + 63 - s_begin) >> 5) + 1;

  const int r4 = lane >> 2, c4 = lane & 3;
#define ATTN_STAGE(s0_, b_)                                                              \
  {                                                                                      \
    const int s0v = (s0_);                                                               \
    if (w < 4) {                                                                         \
      _Pragma("unroll")                                                                  \
      for (int p = 0; p < 2; p++)                                                        \
        glds16(kp + (size_t)(s0v + p * 16 + r4) * 512 + g * 128 + w * 32 + c4 * 8,       \
               &Ks[b_][w][p * 512]);                                                     \
    } else {                                                                             \
      const int wv = w - 4;                                                              \
      _Pragma("unroll")                                                                  \
      for (int p = 0; p < 2; p++)                                                        \
        glds16(vtg + (size_t)(g * 128 + wv * 32 + p * 16 + r4) * 4096 + s0v + c4 * 8,    \
               &Vt[b_][wv * 1024 + p * 512]);                                            \
    }                                                                                    \
  }

  ATTN_STAGE(s_begin, 0);

  for (int c = 0; c < nch; ++c) {
    const int s0 = s_begin + c * 32;
    const int b = c & 1;
    __syncthreads();                       // drain glds for chunk c (uniform)
    if (c + 1 < nch) ATTN_STAGE(s_begin + (c + 1) * 32, (c + 1) & 1);

    if (s0 + 31 >= t0w - 512 && s0 <= t0w + 31) {
      // ---- S^T = K * Q^T, permuted key rows
      f32x4 sacc[2][2];
      sacc[0][0] = fzero; sacc[0][1] = fzero; sacc[1][0] = fzero; sacc[1][1] = fzero;
      const int permBase = ((l15 >> 2) << 3) + (l15 & 3);   // + 4*kt
#pragma unroll
      for (int kb = 0; kb < 4; kb++) {
        short8 af0 = *(const short8*)&Ks[b][kb][(permBase + 0) * 32 + quad * 8];
        short8 af1 = *(const short8*)&Ks[b][kb][(permBase + 4) * 32 + quad * 8];
        sacc[0][0] = __builtin_amdgcn_mfma_f32_16x16x32_bf16(af0, qf[kb][0], sacc[0][0], 0, 0, 0);
        sacc[0][1] = __builtin_amdgcn_mfma_f32_16x16x32_bf16(af0, qf[kb][1], sacc[0][1], 0, 0, 0);
        sacc[1][0] = __builtin_amdgcn_mfma_f32_16x16x32_bf16(af1, qf[kb][0], sacc[1][0], 0, 0, 0);
        sacc[1][1] = __builtin_amdgcn_mfma_f32_16x16x32_bf16(af1, qf[kb][1], sacc[1][1], 0, 0, 0);
      }

      // ---- masked online softmax; key for (kt,r) = s0 + quad*8 + kt*4 + r
      short8 pb[2];
      float alpha[2];
#pragma unroll
      for (int qt = 0; qt < 2; qt++) {
        const int tq = t0w + qt * 16 + l15;
        float vals[8];
        float cmax = NEG_INF;
#pragma unroll
        for (int kt = 0; kt < 2; kt++)
#pragma unroll
          for (int r = 0; r < 4; r++) {
            const int s = s0 + quad * 8 + kt * 4 + r;
            const bool ok = (unsigned)(tq - s) <= 512u;
            const float v = ok ? sacc[kt][qt][r] * scale : NEG_INF;
            vals[kt * 4 + r] = v;
            cmax = fmaxf(cmax, v);
          }
        cmax = fmaxf(cmax, __shfl_xor(cmax, 16));
        cmax = fmaxf(cmax, __shfl_xor(cmax, 32));
        const float Mnew = fmaxf(Mrow[qt], cmax);
        alpha[qt] = __expf(Mrow[qt] - Mnew);
        Mrow[qt] = Mnew;
        float csum = 0.f;
#pragma unroll
        for (int j = 0; j < 8; j++) {
          const float p = __expf(vals[j] - Mnew);
          csum += p;
          pb[qt][j] = (short)f2b(p);
        }
        csum += __shfl_xor(csum, 16);
        csum += __shfl_xor(csum, 32);
        Lrow[qt] = Lrow[qt] * alpha[qt] + csum;
      }

      // ---- O^T += V^T * P^T
#pragma unroll
      for (int db = 0; db < 8; db++) {
        short8 vf = *(const short8*)&Vt[b][(db * 16 + l15) * 32 + quad * 8];
#pragma unroll
        for (int qt = 0; qt < 2; qt++) {
          oacc[db][qt][0] *= alpha[qt]; oacc[db][qt][1] *= alpha[qt];
          oacc[db][qt][2] *= alpha[qt]; oacc[db][qt][3] *= alpha[qt];
          oacc[db][qt] = __builtin_amdgcn_mfma_f32_16x16x32_bf16(vf, pb[qt], oacc[db][qt], 0, 0, 0);
        }
      }
    }
  }
#undef ATTN_STAGE

#pragma unroll
  for (int qt = 0; qt < 2; qt++) {
    const float invL = 1.f / Lrow[qt];
    unsigned short* orow = op + (size_t)(t0w + qt * 16 + l15) * 2048 + h * 128;
#pragma unroll
    for (int db = 0; db < 8; db++) {
      u16x4 o;
#pragma unroll
      for (int r = 0; r < 4; r++) o[r] = f2b(oacc[db][qt][r] * invL);
      *(u16x4*)(orow + db * 16 + quad * 4) = o;
    }
  }
}

// ---------------------------------------------------------------- launch
extern "C" void kernel_launch(void* const* d_in, const int* in_sizes, int n_in,
                              void* d_out, int out_size, void* d_ws, size_t ws_size,
                              hipStream_t stream) {
  const float* x  = (const float*)d_in[0];
  const float* wq = (const float*)d_in[1];
  const float* wk = (const float*)d_in[2];
  const float* wv = (const float*)d_in[3];
  const float* wo = (const float*)d_in[4];
  float* out = (float*)d_out;
  char* ws = (char*)d_ws;

  // workspace map (~63 MB); attnb aliases xb (dead after gemm256 qkv)
  unsigned short* xb    = (unsigned short*)(ws + 0);           // 16,777,216 B
  unsigned short* wqkv  = (unsigned short*)(ws + 16777216);    // 12,582,912 B
  unsigned short* wob   = (unsigned short*)(ws + 29360128);    //  8,388,608 B
  unsigned short* qb    = (unsigned short*)(ws + 37748736);    // 16,777,216 B
  unsigned short* kbuf  = (unsigned short*)(ws + 54525952);    //  4,194,304 B
  unsigned short* vtg   = (unsigned short*)(ws + 58720256);    //  4,194,304 B
  unsigned short* attnb = xb;

  static bool attr_done = false;
  if (!attr_done) {   // allow 128 KiB dynamic LDS (host-side, not stream-ordered)
    hipFuncSetAttribute(reinterpret_cast<const void*>(gemm256),
                        hipFuncAttributeMaxDynamicSharedMemorySize, 131072);
    attr_done = true;
  }

  cast_all<<<18432, 256, 0, stream>>>(x, wq, wk, wv, wo, (unsigned short*)ws);

  // qkv proj + fused RoPE + fused V-transpose (256^2 read-ahead 8-phase; N=3072)
  gemm256<<<dim3(16, 12), 512, 131072, stream>>>(xb, wqkv, 2048, 1,
                                                 qb, kbuf, vtg, nullptr, 0);

  attn_fwd<<<dim3(64, 4), 512, 0, stream>>>(qb, kbuf, vtg, attnb);

  // out = attn @ wo^T  (4096 x 2048, K=2048), fp32 out
  gemm256<<<dim3(16, 8), 512, 131072, stream>>>(attnb, wob, 2048, 0,
                                                nullptr, nullptr, nullptr, out, 2048);
}

// Round 4
// 248.623 us; speedup vs baseline: 1.1449x; 1.0532x over previous
//
#include <hip/hip_runtime.h>

typedef __attribute__((ext_vector_type(8))) short short8;
typedef __attribute__((ext_vector_type(4))) float f32x4;
typedef __attribute__((ext_vector_type(4))) unsigned short u16x4;

__device__ __forceinline__ unsigned short f2b(float f) {
  unsigned int u = __float_as_uint(f);
  u += 0x7fffu + ((u >> 16) & 1u);   // RNE
  return (unsigned short)(u >> 16);
}
__device__ __forceinline__ void glds16(const void* g, void* l) {
  __builtin_amdgcn_global_load_lds(
      (const __attribute__((address_space(1))) unsigned int*)g,
      (__attribute__((address_space(3))) unsigned int*)l, 16, 0, 0);
}

// ------------------------------------------------- fused cast: all 5 inputs -> bf16
__global__ __launch_bounds__(256) void cast_all(const float* __restrict__ x,
                                                const float* __restrict__ wq,
                                                const float* __restrict__ wk,
                                                const float* __restrict__ wv,
                                                const float* __restrict__ wo,
                                                unsigned short* __restrict__ dst) {
  const int i = blockIdx.x * 256 + threadIdx.x;   // < 4,718,592 (grid exact)
  const float* s;
  int off;
  if (i < 2097152)      { s = x;  off = i; }
  else if (i < 3145728) { s = wq; off = i - 2097152; }
  else if (i < 3407872) { s = wk; off = i - 3145728; }
  else if (i < 3670016) { s = wv; off = i - 3407872; }
  else                  { s = wo; off = i - 3670016; }
  f32x4 v = ((const f32x4*)s)[off];
  u16x4 o;
  o[0] = f2b(v[0]); o[1] = f2b(v[1]); o[2] = f2b(v[2]); o[3] = f2b(v[3]);
  ((u16x4*)dst)[i] = o;
}

// ------------------------------------------------------------------ 256x256 8-phase GEMM
// (unchanged from round 3 — see comments there; used for the qkv projection, mode=1)
__global__ __launch_bounds__(512, 2) void gemm256(
    const unsigned short* __restrict__ A, const unsigned short* __restrict__ B,
    const int Karg, const int mode,
    unsigned short* __restrict__ qb, unsigned short* __restrict__ kb,
    unsigned short* __restrict__ vtg, float* __restrict__ Cout, const int Narg) {
  extern __shared__ char smem[];   // [2 dbuf][A:2x16K | B:2x16K] = 131072 B
  const int tid = threadIdx.x;
  const int w = tid >> 6, lane = tid & 63;
  const int quad = lane >> 4, l15 = lane & 15;
  const int wm = w >> 2, wn = w & 3;
  const int m0 = blockIdx.x * 256, n0 = blockIdx.y * 256;

  int nb[4];
#pragma unroll
  for (int ni = 0; ni < 4; ++ni) {
    const int bbi = (wn & 1) * 4 + ni;
    nb[ni] = mode ? ((bbi & 1) ? 4 + (bbi >> 1) : (bbi >> 1)) : bbi;
  }

  const int fragOff = l15 * 64 + ((quad * 16) ^ ((l15 & 8) << 2));
  char* const aWave = smem + wm * 16384;               // + dbuf*65536
  char* const bWave = smem + 32768 + (wn >> 1) * 16384;

  const int sr = lane >> 2;
  const int sc = ((lane & 3) * 8) ^ ((lane & 32) ? 16 : 0);   // bf16 col, pre-swizzled
  const unsigned short* const Abase = A + (size_t)(m0 + (w >> 1) * 16 + sr) * 2048 + (w & 1) * 32 + sc;
  const unsigned short* const Bbase = B + (size_t)(n0 + (w >> 1) * 16 + sr) * 2048 + (w & 1) * 32 + sc;

#define BARF()                            \
  asm volatile("" ::: "memory");          \
  __builtin_amdgcn_s_barrier();           \
  asm volatile("" ::: "memory");

#define STAGE_AJ(h, tt, jj)                                                              \
  {                                                                                      \
    const int t_ = ((tt) < 32) ? (tt) : 31;                                              \
    glds16(Abase + (size_t)(h) * (128 * 2048) + (jj) * (64 * 2048) + (size_t)t_ * 64,    \
           smem + (t_ & 1) * 65536 + (h) * 16384 + (jj) * 8192 + w * 1024);              \
  }
#define STAGE_B2(h, tt)                                                                  \
  {                                                                                      \
    const int t_ = ((tt) < 32) ? (tt) : 31;                                              \
    char* const d_ = smem + (t_ & 1) * 65536 + 32768 + (h) * 16384 + w * 1024;           \
    glds16(Bbase + (size_t)(h) * (128 * 2048) + (size_t)t_ * 64, d_);                    \
    glds16(Bbase + (size_t)(h) * (128 * 2048) + (64 * 2048) + (size_t)t_ * 64, d_ + 8192); \
  }
#define RD_A(dst, c, MI0)                                                                \
  _Pragma("unroll") for (int mi = 0; mi < 4; ++mi)                                       \
  _Pragma("unroll") for (int kk = 0; kk < 2; ++kk)                                       \
      dst[mi][kk] = *(const short8*)(aWave + (c) * 65536 + (((MI0) + mi) * 2 + kk) * 1024 + fragOff);
#define RD_B(dst, c, NI0)                                                                \
  _Pragma("unroll") for (int ni = 0; ni < 2; ++ni)                                       \
  _Pragma("unroll") for (int kk = 0; kk < 2; ++kk)                                       \
      dst[ni][kk] = *(const short8*)(bWave + (c) * 65536 + (nb[(NI0) + ni] * 2 + kk) * 1024 + fragOff);

  f32x4 acc[8][4];
  const f32x4 fz = {0.f, 0.f, 0.f, 0.f};
#pragma unroll
  for (int i = 0; i < 8; ++i)
#pragma unroll
    for (int j = 0; j < 4; ++j) acc[i][j] = fz;

  short8 af[4][2], blo[2][2], bhi[2][2];

#define MFMA_Q(MOFF, NOFF, BF)                                                   \
  _Pragma("unroll") for (int mi = 0; mi < 4; ++mi)                               \
  _Pragma("unroll") for (int ni = 0; ni < 2; ++ni)                               \
  _Pragma("unroll") for (int kk = 0; kk < 2; ++kk)                               \
      acc[(MOFF) + mi][(NOFF) + ni] = __builtin_amdgcn_mfma_f32_16x16x32_bf16(   \
          af[mi][kk], BF[ni][kk], acc[(MOFF) + mi][(NOFF) + ni], 0, 0, 0);

  STAGE_AJ(0, 0, 0) STAGE_AJ(1, 0, 0) STAGE_B2(0, 0) STAGE_B2(1, 0) STAGE_AJ(0, 0, 1) STAGE_AJ(1, 0, 1)
  STAGE_AJ(0, 1, 0) STAGE_AJ(1, 1, 0) STAGE_B2(0, 1) STAGE_B2(1, 1) STAGE_AJ(0, 1, 1) STAGE_AJ(1, 1, 1)
  asm volatile("s_waitcnt vmcnt(8)" ::: "memory");   // tile0 resident; tile1 in flight
  __builtin_amdgcn_s_barrier();
  asm volatile("" ::: "memory");
  RD_A(af, 0, 0)    // Alo(0)
  RD_B(blo, 0, 0)   // Blo(0)

#define HALF(c, tt)                                                                  \
  /* P1 */                                                                           \
  BARF()                                                                             \
  __builtin_amdgcn_s_setprio(1); MFMA_Q(0, 0, blo) __builtin_amdgcn_s_setprio(0);    \
  RD_B(bhi, (c), 2)                                                                  \
  BARF()                                                                             \
  /* P2 */ STAGE_AJ(0, (tt) + 2, 0) STAGE_AJ(1, (tt) + 2, 0)                         \
  BARF()                                                                             \
  __builtin_amdgcn_s_setprio(1); MFMA_Q(0, 2, bhi) __builtin_amdgcn_s_setprio(0);    \
  RD_A(af, (c), 4)                                                                   \
  BARF()                                                                             \
  /* P3 */ STAGE_B2(0, (tt) + 2) STAGE_B2(1, (tt) + 2)                               \
  BARF()                                                                             \
  __builtin_amdgcn_s_setprio(1); MFMA_Q(4, 2, bhi) __builtin_amdgcn_s_setprio(0);    \
  BARF()                                                                             \
  /* P4 */ STAGE_AJ(0, (tt) + 2, 1) STAGE_AJ(1, (tt) + 2, 1)                         \
  BARF()                                                                             \
  __builtin_amdgcn_s_setprio(1); MFMA_Q(4, 0, blo) __builtin_amdgcn_s_setprio(0);    \
  asm volatile("s_waitcnt vmcnt(8)" ::: "memory");                                   \
  RD_A(af, (c) ^ 1, 0)                                                               \
  RD_B(blo, (c) ^ 1, 0)

#pragma unroll 1
  for (int T = 0; T < 32; T += 2) {
    HALF(0, T)
    HALF(1, T + 1)
  }
  asm volatile("s_waitcnt vmcnt(0)" ::: "memory");   // drain clamped tail rewrites
#undef HALF
#undef MFMA_Q
#undef RD_A
#undef RD_B
#undef STAGE_AJ
#undef STAGE_B2
#undef BARF

  // ------------------------------------------------------------------ epilogues
  if (mode == 0) {
    const int colBase = n0 + wn * 64;
#pragma unroll
    for (int mi = 0; mi < 8; ++mi) {
      const int row = m0 + wm * 128 + mi * 16 + quad * 4;
#pragma unroll
      for (int ni = 0; ni < 4; ++ni) {
        const int col = colBase + ni * 16 + l15;
#pragma unroll
        for (int r = 0; r < 4; ++r)
          Cout[(size_t)(row + r) * 2048 + col] = acc[mi][ni][r];
      }
    }
    return;
  }

  const int y = blockIdx.y;            // 0-7: Q heads 2y,2y+1 | 8-9: K | 10-11: V
  const int tb0 = m0 + wm * 128;
  if (y >= 10) {
    const int g = (y - 10) * 2 + (wn >> 1);
#pragma unroll
    for (int mi = 0; mi < 8; ++mi) {
      const int tb = tb0 + mi * 16 + quad * 4;
#pragma unroll
      for (int ni = 0; ni < 4; ++ni) {
        const int d = nb[ni] * 16 + l15;
        u16x4 o;
#pragma unroll
        for (int r = 0; r < 4; ++r) o[r] = f2b(acc[mi][ni][r]);
        *(u16x4*)(vtg + (size_t)(g * 128 + d) * 4096 + tb) = o;
      }
    }
  } else {
    unsigned short* dst;
    int stride, hoff;
    if (y < 8) { dst = qb; stride = 2048; hoff = (y * 2 + (wn >> 1)) * 128; }
    else       { dst = kb; stride = 512;  hoff = ((y - 8) * 2 + (wn >> 1)) * 128; }
    const float c2 = 0.20762050593045889f;   // log2(10000)/64
    const float inv2pi = 0.15915494309189535f;
#pragma unroll
    for (int j = 0; j < 2; ++j) {
      const int i = ((wn & 1) * 2 + j) * 16 + l15;            // rope dim, < 64
      const float inv_rev = exp2f(-(float)i * c2) * inv2pi;   // freq in revolutions
#pragma unroll
      for (int mi = 0; mi < 8; ++mi) {
#pragma unroll
        for (int r = 0; r < 4; ++r) {
          const int t = tb0 + mi * 16 + quad * 4 + r;
          float rev = (float)t * inv_rev;
          rev -= floorf(rev);                    // [0,1) for HW v_sin/v_cos
          const float sn = __builtin_amdgcn_sinf(rev);
          const float cs = __builtin_amdgcn_cosf(rev);
          const float x1 = acc[mi][2 * j][r], x2 = acc[mi][2 * j + 1][r];
          unsigned short* p = dst + (size_t)t * stride + hoff + i;
          p[0]  = f2b(x1 * cs - x2 * sn);
          p[64] = f2b(x1 * sn + x2 * cs);
        }
      }
    }
  }
}

// ------------------------------------------------------------------ 128x256 2-phase GEMM
// C = A * B^T fp32, BM=128, BN=256, BK=64 (K=2048, 32 tiles), 8 waves (2Mx4N),
// per-wave 64x64 output (acc[4][4]), 96 KiB LDS (2 dbuf x [A 16K | B.h0 16K | B.h1 16K]).
// Same swizzled 16x32-subtile layout as gemm256. Grid (32,8) = 256 blocks -> full chip
// (the mode-0 gemm256 ran 128 blocks = half the CUs idle).
// 2-phase read-ahead schedule, region-lifetime rule (>=2 barriers + consuming MFMA):
//   P1: stage B(T+1)x4 -> buf c^1 | BAR | MFMA n-lo | read bhi(c)      | BAR
//   P2: stage A(T+2)x2 -> buf c   | BAR | MFMA n-hi | vmcnt(2) | read af,blo(c^1) | BAR
// Proofs: B(c^1) overwrite at P1-top is 3 barriers past bhi(T-1) read, consumed by
// prev P2 MFMA. A(c) overwrite at P2-top is 2 barriers past af(T) read (end of prev
// iter), consumed by P1 MFMA. Gate: after gate, outstanding=[A(T+1)x2]; +B(T+1)x4
// +A(T+2)x2 = 8 -> vmcnt(2) drains A(T+1),B(T+1) exactly before their ds_reads.
// Prologue {A0x2,B0x4,A1x2; vmcnt(2)} establishes the invariant. Tail: staged index
// clamped to 31 (identical-byte rewrite, WAR-benign, uniform counts).
__global__ __launch_bounds__(512, 2) void gemm128(const unsigned short* __restrict__ A,
                                                  const unsigned short* __restrict__ B,
                                                  float* __restrict__ Cout) {
  extern __shared__ char smem[];   // 2 x 49152 B
  const int tid = threadIdx.x;
  const int w = tid >> 6, lane = tid & 63;
  const int quad = lane >> 4, l15 = lane & 15;
  const int wm = w >> 2, wn = w & 3;
  const int m0 = blockIdx.x * 128, n0 = blockIdx.y * 256;

  const int fragOff = l15 * 64 + ((quad * 16) ^ ((l15 & 8) << 2));
  char* const aWave = smem;                              // + dbuf*49152
  char* const bWave = smem + 16384 + (wn >> 1) * 16384;

  const int sr = lane >> 2;
  const int sc = ((lane & 3) * 8) ^ ((lane & 32) ? 16 : 0);   // bf16 col, pre-swizzled
  const unsigned short* const Abase = A + (size_t)(m0 + (w >> 1) * 16 + sr) * 2048 + (w & 1) * 32 + sc;
  const unsigned short* const Bbase = B + (size_t)(n0 + (w >> 1) * 16 + sr) * 2048 + (w & 1) * 32 + sc;

#define BARF()                            \
  asm volatile("" ::: "memory");          \
  __builtin_amdgcn_s_barrier();           \
  asm volatile("" ::: "memory");

#define G_STAGE_A(tt)                                                                    \
  {                                                                                      \
    const int t_ = ((tt) < 32) ? (tt) : 31;                                              \
    char* const d_ = smem + (t_ & 1) * 49152 + w * 1024;                                 \
    glds16(Abase + (size_t)t_ * 64, d_);                                                 \
    glds16(Abase + (64 * 2048) + (size_t)t_ * 64, d_ + 8192);                            \
  }
#define G_STAGE_B(h, tt)                                                                 \
  {                                                                                      \
    const int t_ = ((tt) < 32) ? (tt) : 31;                                              \
    char* const d_ = smem + (t_ & 1) * 49152 + 16384 + (h) * 16384 + w * 1024;           \
    glds16(Bbase + (size_t)(h) * (128 * 2048) + (size_t)t_ * 64, d_);                    \
    glds16(Bbase + (size_t)(h) * (128 * 2048) + (64 * 2048) + (size_t)t_ * 64, d_ + 8192); \
  }
#define G_RD_A(c)                                                                        \
  _Pragma("unroll") for (int mi = 0; mi < 4; ++mi)                                       \
  _Pragma("unroll") for (int kk = 0; kk < 2; ++kk)                                       \
      af[mi][kk] = *(const short8*)(aWave + (c) * 49152 + ((wm * 4 + mi) * 2 + kk) * 1024 + fragOff);
#define G_RD_B(dst, c, NI0)                                                              \
  _Pragma("unroll") for (int ni = 0; ni < 2; ++ni)                                       \
  _Pragma("unroll") for (int kk = 0; kk < 2; ++kk)                                       \
      dst[ni][kk] = *(const short8*)(bWave + (c) * 49152 + (((wn & 1) * 4 + (NI0) + ni) * 2 + kk) * 1024 + fragOff);

  f32x4 acc[4][4];
  const f32x4 fz = {0.f, 0.f, 0.f, 0.f};
#pragma unroll
  for (int i = 0; i < 4; ++i)
#pragma unroll
    for (int j = 0; j < 4; ++j) acc[i][j] = fz;

  short8 af[4][2], blo[2][2], bhi[2][2];

#define G_MFMA(NOFF, BF)                                                         \
  _Pragma("unroll") for (int mi = 0; mi < 4; ++mi)                               \
  _Pragma("unroll") for (int ni = 0; ni < 2; ++ni)                               \
  _Pragma("unroll") for (int kk = 0; kk < 2; ++kk)                               \
      acc[mi][(NOFF) + ni] = __builtin_amdgcn_mfma_f32_16x16x32_bf16(            \
          af[mi][kk], BF[ni][kk], acc[mi][(NOFF) + ni], 0, 0, 0);

  // prologue: A(0)x2, B(0)x4, A(1)x2; drain tile0, leave A(1) in flight
  G_STAGE_A(0) G_STAGE_B(0, 0) G_STAGE_B(1, 0) G_STAGE_A(1)
  asm volatile("s_waitcnt vmcnt(2)" ::: "memory");
  __builtin_amdgcn_s_barrier();
  asm volatile("" ::: "memory");
  G_RD_A(0)
  G_RD_B(blo, 0, 0)

#define G_TILE(c, tt)                                                                \
  /* P1 */ G_STAGE_B(0, (tt) + 1) G_STAGE_B(1, (tt) + 1)                             \
  BARF()                                                                             \
  __builtin_amdgcn_s_setprio(1); G_MFMA(0, blo) __builtin_amdgcn_s_setprio(0);       \
  G_RD_B(bhi, (c), 2)                                                                \
  BARF()                                                                             \
  /* P2 */ G_STAGE_A((tt) + 2)                                                       \
  BARF()                                                                             \
  __builtin_amdgcn_s_setprio(1); G_MFMA(2, bhi) __builtin_amdgcn_s_setprio(0);       \
  asm volatile("s_waitcnt vmcnt(2)" ::: "memory");                                   \
  G_RD_A((c) ^ 1)                                                                    \
  G_RD_B(blo, (c) ^ 1, 0)                                                            \
  BARF()

#pragma unroll 1
  for (int T = 0; T < 32; T += 2) {
    G_TILE(0, T)
    G_TILE(1, T + 1)
  }
  asm volatile("s_waitcnt vmcnt(0)" ::: "memory");   // drain clamped tail rewrites
#undef G_TILE
#undef G_MFMA
#undef G_RD_A
#undef G_RD_B
#undef G_STAGE_A
#undef G_STAGE_B
#undef BARF

  const int colBase = n0 + wn * 64;
#pragma unroll
  for (int mi = 0; mi < 4; ++mi) {
    const int row = m0 + wm * 64 + mi * 16 + quad * 4;
#pragma unroll
    for (int ni = 0; ni < 4; ++ni) {
      const int col = colBase + ni * 16 + l15;
#pragma unroll
      for (int r = 0; r < 4; ++r)
        Cout[(size_t)(row + r) * 2048 + col] = acc[mi][ni][r];
    }
  }
}

// ------------------------------------------------------------ windowed GQA attention
// Block: 8 waves, 64 queries, one kv group. wave w: head g*4+(w&3), query-half w>>2.
__global__ __launch_bounds__(512) void attn_fwd(const unsigned short* __restrict__ qp,
                                                const unsigned short* __restrict__ kp,
                                                const unsigned short* __restrict__ vtg,
                                                unsigned short* __restrict__ op) {
  __shared__ unsigned short Ks[2][4][1024];   // [buf][kb][key*32+d']
  __shared__ unsigned short Vt[2][4096];      // [buf][d*32+key]
  const int tid = threadIdx.x;
  const int w = tid >> 6, lane = tid & 63;
  const int quad = lane >> 4, l15 = lane & 15;
  const int t0 = blockIdx.x * 64;
  const int g = blockIdx.y;
  const int h = g * 4 + (w & 3);
  const int t0w = t0 + (w >> 2) * 32;         // this wave's 32-query base
  const f32x4 fzero = {0.f, 0.f, 0.f, 0.f};
  const float scale = 0.088388347648318447f;  // 1/sqrt(128)
  const float NEG_INF = -__builtin_inff();

  short8 qf[4][2];
#pragma unroll
  for (int qt = 0; qt < 2; qt++) {
    const unsigned short* qrow = qp + (size_t)(t0w + qt * 16 + l15) * 2048 + h * 128 + quad * 8;
#pragma unroll
    for (int kb = 0; kb < 4; kb++) qf[kb][qt] = *(const short8*)(qrow + kb * 32);
  }

  f32x4 oacc[8][2];
#pragma unroll
  for (int db = 0; db < 8; db++) { oacc[db][0] = fzero; oacc[db][1] = fzero; }
  float Mrow[2] = {-1.0e30f, -1.0e30f}, Lrow[2] = {0.f, 0.f};

  const int s_begin = (t0 >= 512) ? (t0 - 512) : 0;
  const int nch = ((t0 + 63 - s_begin) >> 5) + 1;

  const int r4 = lane >> 2, c4 = lane & 3;
#define ATTN_STAGE(s0_, b_)                                                              \
  {                                                                                      \
    const int s0v = (s0_);                                                               \
    if (w < 4) {                                                                         \
      _Pragma("unroll")                                                                  \
      for (int p = 0; p < 2; p++)                                                        \
        glds16(kp + (size_t)(s0v + p * 16 + r4) * 512 + g * 128 + w * 32 + c4 * 8,       \
               &Ks[b_][w][p * 512]);                                                     \
    } else {                                                                             \
      const int wv = w - 4;                                                              \
      _Pragma("unroll")                                                                  \
      for (int p = 0; p < 2; p++)                                                        \
        glds16(vtg + (size_t)(g * 128 + wv * 32 + p * 16 + r4) * 4096 + s0v + c4 * 8,    \
               &Vt[b_][wv * 1024 + p * 512]);                                            \
    }                                                                                    \
  }

  ATTN_STAGE(s_begin, 0);

  for (int c = 0; c < nch; ++c) {
    const int s0 = s_begin + c * 32;
    const int b = c & 1;
    __syncthreads();                       // drain glds for chunk c (uniform)
    if (c + 1 < nch) ATTN_STAGE(s_begin + (c + 1) * 32, (c + 1) & 1);

    if (s0 + 31 >= t0w - 512 && s0 <= t0w + 31) {
      // ---- S^T = K * Q^T, permuted key rows
      f32x4 sacc[2][2];
      sacc[0][0] = fzero; sacc[0][1] = fzero; sacc[1][0] = fzero; sacc[1][1] = fzero;
      const int permBase = ((l15 >> 2) << 3) + (l15 & 3);   // + 4*kt
#pragma unroll
      for (int kb = 0; kb < 4; kb++) {
        short8 af0 = *(const short8*)&Ks[b][kb][(permBase + 0) * 32 + quad * 8];
        short8 af1 = *(const short8*)&Ks[b][kb][(permBase + 4) * 32 + quad * 8];
        sacc[0][0] = __builtin_amdgcn_mfma_f32_16x16x32_bf16(af0, qf[kb][0], sacc[0][0], 0, 0, 0);
        sacc[0][1] = __builtin_amdgcn_mfma_f32_16x16x32_bf16(af0, qf[kb][1], sacc[0][1], 0, 0, 0);
        sacc[1][0] = __builtin_amdgcn_mfma_f32_16x16x32_bf16(af1, qf[kb][0], sacc[1][0], 0, 0, 0);
        sacc[1][1] = __builtin_amdgcn_mfma_f32_16x16x32_bf16(af1, qf[kb][1], sacc[1][1], 0, 0, 0);
      }

      // ---- masked online softmax; key for (kt,r) = s0 + quad*8 + kt*4 + r
      short8 pb[2];
      float alpha[2];
#pragma unroll
      for (int qt = 0; qt < 2; qt++) {
        const int tq = t0w + qt * 16 + l15;
        float vals[8];
        float cmax = NEG_INF;
#pragma unroll
        for (int kt = 0; kt < 2; kt++)
#pragma unroll
          for (int r = 0; r < 4; r++) {
            const int s = s0 + quad * 8 + kt * 4 + r;
            const bool ok = (unsigned)(tq - s) <= 512u;
            const float v = ok ? sacc[kt][qt][r] * scale : NEG_INF;
            vals[kt * 4 + r] = v;
            cmax = fmaxf(cmax, v);
          }
        cmax = fmaxf(cmax, __shfl_xor(cmax, 16));
        cmax = fmaxf(cmax, __shfl_xor(cmax, 32));
        const float Mnew = fmaxf(Mrow[qt], cmax);
        alpha[qt] = __expf(Mrow[qt] - Mnew);
        Mrow[qt] = Mnew;
        float csum = 0.f;
#pragma unroll
        for (int j = 0; j < 8; j++) {
          const float p = __expf(vals[j] - Mnew);
          csum += p;
          pb[qt][j] = (short)f2b(p);
        }
        csum += __shfl_xor(csum, 16);
        csum += __shfl_xor(csum, 32);
        Lrow[qt] = Lrow[qt] * alpha[qt] + csum;
      }

      // ---- O^T += V^T * P^T
#pragma unroll
      for (int db = 0; db < 8; db++) {
        short8 vf = *(const short8*)&Vt[b][(db * 16 + l15) * 32 + quad * 8];
#pragma unroll
        for (int qt = 0; qt < 2; qt++) {
          oacc[db][qt][0] *= alpha[qt]; oacc[db][qt][1] *= alpha[qt];
          oacc[db][qt][2] *= alpha[qt]; oacc[db][qt][3] *= alpha[qt];
          oacc[db][qt] = __builtin_amdgcn_mfma_f32_16x16x32_bf16(vf, pb[qt], oacc[db][qt], 0, 0, 0);
        }
      }
    }
  }
#undef ATTN_STAGE

#pragma unroll
  for (int qt = 0; qt < 2; qt++) {
    const float invL = 1.f / Lrow[qt];
    unsigned short* orow = op + (size_t)(t0w + qt * 16 + l15) * 2048 + h * 128;
#pragma unroll
    for (int db = 0; db < 8; db++) {
      u16x4 o;
#pragma unroll
      for (int r = 0; r < 4; r++) o[r] = f2b(oacc[db][qt][r] * invL);
      *(u16x4*)(orow + db * 16 + quad * 4) = o;
    }
  }
}

// ---------------------------------------------------------------- launch
extern "C" void kernel_launch(void* const* d_in, const int* in_sizes, int n_in,
                              void* d_out, int out_size, void* d_ws, size_t ws_size,
                              hipStream_t stream) {
  const float* x  = (const float*)d_in[0];
  const float* wq = (const float*)d_in[1];
  const float* wk = (const float*)d_in[2];
  const float* wv = (const float*)d_in[3];
  const float* wo = (const float*)d_in[4];
  float* out = (float*)d_out;
  char* ws = (char*)d_ws;

  // workspace map (~63 MB); attnb aliases xb (dead after gemm256 qkv)
  unsigned short* xb    = (unsigned short*)(ws + 0);           // 16,777,216 B
  unsigned short* wqkv  = (unsigned short*)(ws + 16777216);    // 12,582,912 B
  unsigned short* wob   = (unsigned short*)(ws + 29360128);    //  8,388,608 B
  unsigned short* qb    = (unsigned short*)(ws + 37748736);    // 16,777,216 B
  unsigned short* kbuf  = (unsigned short*)(ws + 54525952);    //  4,194,304 B
  unsigned short* vtg   = (unsigned short*)(ws + 58720256);    //  4,194,304 B
  unsigned short* attnb = xb;

  static bool attr_done = false;
  if (!attr_done) {   // allow big dynamic LDS (host-side, not stream-ordered)
    hipFuncSetAttribute(reinterpret_cast<const void*>(gemm256),
                        hipFuncAttributeMaxDynamicSharedMemorySize, 131072);
    hipFuncSetAttribute(reinterpret_cast<const void*>(gemm128),
                        hipFuncAttributeMaxDynamicSharedMemorySize, 98304);
    attr_done = true;
  }

  cast_all<<<18432, 256, 0, stream>>>(x, wq, wk, wv, wo, (unsigned short*)ws);

  // qkv proj + fused RoPE + fused V-transpose (256^2 read-ahead 8-phase; N=3072)
  gemm256<<<dim3(16, 12), 512, 131072, stream>>>(xb, wqkv, 2048, 1,
                                                 qb, kbuf, vtg, nullptr, 0);

  attn_fwd<<<dim3(64, 4), 512, 0, stream>>>(qb, kbuf, vtg, attnb);

  // out = attn @ wo^T  (4096 x 2048, K=2048), fp32 out — 128x256 tiles, 256 blocks
  gemm128<<<dim3(32, 8), 512, 98304, stream>>>(attnb, wob, out);
}

// Round 5
// 244.571 us; speedup vs baseline: 1.1638x; 1.0166x over previous
//
#include <hip/hip_runtime.h>

typedef __attribute__((ext_vector_type(8))) short short8;
typedef __attribute__((ext_vector_type(4))) float f32x4;
typedef __attribute__((ext_vector_type(4))) unsigned short u16x4;

__device__ __forceinline__ unsigned short f2b(float f) {
  unsigned int u = __float_as_uint(f);
  u += 0x7fffu + ((u >> 16) & 1u);   // RNE
  return (unsigned short)(u >> 16);
}
__device__ __forceinline__ void glds16(const void* g, void* l) {
  __builtin_amdgcn_global_load_lds(
      (const __attribute__((address_space(1))) unsigned int*)g,
      (__attribute__((address_space(3))) unsigned int*)l, 16, 0, 0);
}

// ------------------------------------------------- fused cast: all 5 inputs -> bf16
__global__ __launch_bounds__(256) void cast_all(const float* __restrict__ x,
                                                const float* __restrict__ wq,
                                                const float* __restrict__ wk,
                                                const float* __restrict__ wv,
                                                const float* __restrict__ wo,
                                                unsigned short* __restrict__ dst) {
  const int i = blockIdx.x * 256 + threadIdx.x;   // < 4,718,592 (grid exact)
  const float* s;
  int off;
  if (i < 2097152)      { s = x;  off = i; }
  else if (i < 3145728) { s = wq; off = i - 2097152; }
  else if (i < 3407872) { s = wk; off = i - 3145728; }
  else if (i < 3670016) { s = wv; off = i - 3407872; }
  else                  { s = wo; off = i - 3670016; }
  f32x4 v = ((const f32x4*)s)[off];
  u16x4 o;
  o[0] = f2b(v[0]); o[1] = f2b(v[1]); o[2] = f2b(v[2]); o[3] = f2b(v[3]);
  ((u16x4*)dst)[i] = o;
}

// ------------------------------------------------------------------ 256x256 8-phase GEMM
// C = A * B^T, BM=BN=256, BK=64 (K=2048, 32 tiles), 8 waves (2Mx4N), 512 threads,
// 128 KiB LDS. Swizzled 16x32-subtile layout (pre-swizzled global src, linear glds).
//
// m201-shape phases (reads at TOP, same-phase use; MFMA kk-OUTER so adjacent MFMAs
// are independent — the (mi,ni,kk) order made RAW-chained pairs, ~41% busy-CU util):
//   P1: vmcnt(8) | rd af<-Alo(T), blo(T) |                  | BAR | MFMA Q1 | BAR
//   P2:          | rd bhi(T)             | stage Aj0(T+2) x2| BAR | MFMA Q2 | BAR
//   P3:          | rd af<-Ahi(T)         | stage B(T+2) x4  | BAR | MFMA Q3 | BAR
//   P4:          |                       | stage Aj1(T+2) x2| BAR | MFMA Q4 | BAR
// WAR rule (r3): every stage is >=1 barrier after the consuming MFMA of its region's
// last read — Aj0 region read@P1/consumed Q1, staged @P2-top (after P1 2nd BAR) OK;
// B regions consumed by Q1(blo)/Q2(bhi), staged @P3-top OK; Aj1 consumed Q3, @P4 OK.
// Gate: vmcnt(8)@P1-top. Induction: at P1(T) outstanding = T's leftovers + T+1's 8;
// gate drains T fully (reads of T follow), leaves T+1's 8. Prologue: 16 stages in
// per-tile unit order, collective vmcnt(8)+barrier (gate-then-barrier = all waves'
// tile-0 stages drained). Tail: staged K-index clamped to 31 (identical-byte rewrite,
// WAR-benign, uniform counts). lgkm waits are compiler-inserted (plain LDS loads).
// mode=1 (qkv): B n-block read permuted (nb) so ni=2j/2j+1 hold rope partners
// (d,d+64) -> thread-local RoPE epilogue. mode=0: plain fp32 C.
__global__ __launch_bounds__(512, 2) void gemm256(
    const unsigned short* __restrict__ A, const unsigned short* __restrict__ B,
    const int Karg, const int mode,
    unsigned short* __restrict__ qb, unsigned short* __restrict__ kb,
    unsigned short* __restrict__ vtg, float* __restrict__ Cout, const int Narg) {
  extern __shared__ char smem[];   // [2 dbuf][A:2x16K | B:2x16K] = 131072 B
  const int tid = threadIdx.x;
  const int w = tid >> 6, lane = tid & 63;
  const int quad = lane >> 4, l15 = lane & 15;
  const int wm = w >> 2, wn = w & 3;
  const int m0 = blockIdx.x * 256, n0 = blockIdx.y * 256;

  int nb[4];
#pragma unroll
  for (int ni = 0; ni < 4; ++ni) {
    const int bbi = (wn & 1) * 4 + ni;
    nb[ni] = mode ? ((bbi & 1) ? 4 + (bbi >> 1) : (bbi >> 1)) : bbi;
  }

  const int fragOff = l15 * 64 + ((quad * 16) ^ ((l15 & 8) << 2));
  char* const aWave = smem + wm * 16384;               // + dbuf*65536
  char* const bWave = smem + 32768 + (wn >> 1) * 16384;

  const int sr = lane >> 2;
  const int sc = ((lane & 3) * 8) ^ ((lane & 32) ? 16 : 0);   // bf16 col, pre-swizzled
  const unsigned short* const Abase = A + (size_t)(m0 + (w >> 1) * 16 + sr) * 2048 + (w & 1) * 32 + sc;
  const unsigned short* const Bbase = B + (size_t)(n0 + (w >> 1) * 16 + sr) * 2048 + (w & 1) * 32 + sc;

#define BARF()                            \
  asm volatile("" ::: "memory");          \
  __builtin_amdgcn_s_barrier();           \
  asm volatile("" ::: "memory");

#define STAGE_AJ(h, tt, jj)                                                              \
  {                                                                                      \
    const int t_ = ((tt) < 32) ? (tt) : 31;                                              \
    glds16(Abase + (size_t)(h) * (128 * 2048) + (jj) * (64 * 2048) + (size_t)t_ * 64,    \
           smem + (t_ & 1) * 65536 + (h) * 16384 + (jj) * 8192 + w * 1024);              \
  }
#define STAGE_B2(h, tt)                                                                  \
  {                                                                                      \
    const int t_ = ((tt) < 32) ? (tt) : 31;                                              \
    char* const d_ = smem + (t_ & 1) * 65536 + 32768 + (h) * 16384 + w * 1024;           \
    glds16(Bbase + (size_t)(h) * (128 * 2048) + (size_t)t_ * 64, d_);                    \
    glds16(Bbase + (size_t)(h) * (128 * 2048) + (64 * 2048) + (size_t)t_ * 64, d_ + 8192); \
  }
#define RD_A(dst, c, MI0)                                                                \
  _Pragma("unroll") for (int mi = 0; mi < 4; ++mi)                                       \
  _Pragma("unroll") for (int kk = 0; kk < 2; ++kk)                                       \
      dst[mi][kk] = *(const short8*)(aWave + (c) * 65536 + (((MI0) + mi) * 2 + kk) * 1024 + fragOff);
#define RD_B(dst, c, NI0)                                                                \
  _Pragma("unroll") for (int ni = 0; ni < 2; ++ni)                                       \
  _Pragma("unroll") for (int kk = 0; kk < 2; ++kk)                                       \
      dst[ni][kk] = *(const short8*)(bWave + (c) * 65536 + (nb[(NI0) + ni] * 2 + kk) * 1024 + fragOff);

  f32x4 acc[8][4];
  const f32x4 fz = {0.f, 0.f, 0.f, 0.f};
#pragma unroll
  for (int i = 0; i < 8; ++i)
#pragma unroll
    for (int j = 0; j < 4; ++j) acc[i][j] = fz;

  short8 af[4][2], blo[2][2], bhi[2][2];

  // kk-OUTER: adjacent MFMAs independent; per-acc kk order preserved (bit-identical)
#define MFMA_Q(MOFF, NOFF, BF)                                                   \
  _Pragma("unroll") for (int kk = 0; kk < 2; ++kk)                               \
  _Pragma("unroll") for (int mi = 0; mi < 4; ++mi)                               \
  _Pragma("unroll") for (int ni = 0; ni < 2; ++ni)                               \
      acc[(MOFF) + mi][(NOFF) + ni] = __builtin_amdgcn_mfma_f32_16x16x32_bf16(   \
          af[mi][kk], BF[ni][kk], acc[(MOFF) + mi][(NOFF) + ni], 0, 0, 0);

  // prologue: tile0 (8 glds) then tile1 (8 glds), per-tile unit order; collective drain
  STAGE_AJ(0, 0, 0) STAGE_AJ(1, 0, 0) STAGE_B2(0, 0) STAGE_B2(1, 0) STAGE_AJ(0, 0, 1) STAGE_AJ(1, 0, 1)
  STAGE_AJ(0, 1, 0) STAGE_AJ(1, 1, 0) STAGE_B2(0, 1) STAGE_B2(1, 1) STAGE_AJ(0, 1, 1) STAGE_AJ(1, 1, 1)
  asm volatile("s_waitcnt vmcnt(8)" ::: "memory");   // own tile0 drained
  BARF()                                             // -> ALL waves' tile0 drained

#define TILE(c, tt)                                                                  \
  /* P1 */ asm volatile("s_waitcnt vmcnt(8)" ::: "memory");                          \
  RD_A(af, (c), 0) RD_B(blo, (c), 0)                                                 \
  BARF()                                                                             \
  __builtin_amdgcn_s_setprio(1); MFMA_Q(0, 0, blo) __builtin_amdgcn_s_setprio(0);    \
  BARF()                                                                             \
  /* P2 */ RD_B(bhi, (c), 2)                                                         \
  STAGE_AJ(0, (tt) + 2, 0) STAGE_AJ(1, (tt) + 2, 0)                                  \
  BARF()                                                                             \
  __builtin_amdgcn_s_setprio(1); MFMA_Q(0, 2, bhi) __builtin_amdgcn_s_setprio(0);    \
  BARF()                                                                             \
  /* P3 */ RD_A(af, (c), 4)                                                          \
  STAGE_B2(0, (tt) + 2) STAGE_B2(1, (tt) + 2)                                        \
  BARF()                                                                             \
  __builtin_amdgcn_s_setprio(1); MFMA_Q(4, 2, bhi) __builtin_amdgcn_s_setprio(0);    \
  BARF()                                                                             \
  /* P4 */ STAGE_AJ(0, (tt) + 2, 1) STAGE_AJ(1, (tt) + 2, 1)                         \
  BARF()                                                                             \
  __builtin_amdgcn_s_setprio(1); MFMA_Q(4, 0, blo) __builtin_amdgcn_s_setprio(0);    \
  BARF()

#pragma unroll 1
  for (int T = 0; T < 32; T += 2) {
    TILE(0, T)
    TILE(1, T + 1)
  }
  asm volatile("s_waitcnt vmcnt(0)" ::: "memory");   // drain clamped tail rewrites
#undef TILE
#undef MFMA_Q
#undef RD_A
#undef RD_B
#undef STAGE_AJ
#undef STAGE_B2
#undef BARF

  // ------------------------------------------------------------------ epilogues
  if (mode == 0) {
    const int colBase = n0 + wn * 64;
#pragma unroll
    for (int mi = 0; mi < 8; ++mi) {
      const int row = m0 + wm * 128 + mi * 16 + quad * 4;
#pragma unroll
      for (int ni = 0; ni < 4; ++ni) {
        const int col = colBase + ni * 16 + l15;
#pragma unroll
        for (int r = 0; r < 4; ++r)
          Cout[(size_t)(row + r) * 2048 + col] = acc[mi][ni][r];
      }
    }
    return;
  }

  const int y = blockIdx.y;            // 0-7: Q heads 2y,2y+1 | 8-9: K | 10-11: V
  const int tb0 = m0 + wm * 128;
  if (y >= 10) {
    const int g = (y - 10) * 2 + (wn >> 1);
#pragma unroll
    for (int mi = 0; mi < 8; ++mi) {
      const int tb = tb0 + mi * 16 + quad * 4;
#pragma unroll
      for (int ni = 0; ni < 4; ++ni) {
        const int d = nb[ni] * 16 + l15;
        u16x4 o;
#pragma unroll
        for (int r = 0; r < 4; ++r) o[r] = f2b(acc[mi][ni][r]);
        *(u16x4*)(vtg + (size_t)(g * 128 + d) * 4096 + tb) = o;
      }
    }
  } else {
    unsigned short* dst;
    int stride, hoff;
    if (y < 8) { dst = qb; stride = 2048; hoff = (y * 2 + (wn >> 1)) * 128; }
    else       { dst = kb; stride = 512;  hoff = ((y - 8) * 2 + (wn >> 1)) * 128; }
    const float c2 = 0.20762050593045889f;   // log2(10000)/64
    const float inv2pi = 0.15915494309189535f;
#pragma unroll
    for (int j = 0; j < 2; ++j) {
      const int i = ((wn & 1) * 2 + j) * 16 + l15;            // rope dim, < 64
      const float inv_rev = exp2f(-(float)i * c2) * inv2pi;   // freq in revolutions
#pragma unroll
      for (int mi = 0; mi < 8; ++mi) {
#pragma unroll
        for (int r = 0; r < 4; ++r) {
          const int t = tb0 + mi * 16 + quad * 4 + r;
          float rev = (float)t * inv_rev;
          rev -= floorf(rev);                    // [0,1) for HW v_sin/v_cos
          const float sn = __builtin_amdgcn_sinf(rev);
          const float cs = __builtin_amdgcn_cosf(rev);
          const float x1 = acc[mi][2 * j][r], x2 = acc[mi][2 * j + 1][r];
          unsigned short* p = dst + (size_t)t * stride + hoff + i;
          p[0]  = f2b(x1 * cs - x2 * sn);
          p[64] = f2b(x1 * sn + x2 * cs);
        }
      }
    }
  }
}

// ------------------------------------------------------------------ 128x256 2-phase GEMM
// C = A * B^T fp32 (wo projection). Grid (32,8) = 256 blocks = full chip. Same
// m201-shape phases + kk-outer MFMA as gemm256:
//   P1: vmcnt(2) | rd af(T), blo(T) | stage B(T+1) x4 | BAR | MFMA n-lo | BAR
//   P2:          | rd bhi(T)        | stage A(T+2) x2 | BAR | MFMA n-hi | BAR
// WAR: B(c^1) overwrite @P1-top is after P2(T-1)'s post-MFMA BAR (bhi(T-1) consumed
// Q2); A(c) overwrite @P2-top after P1's post-MFMA BAR (af consumed Q1 — af also used
// by Q2 from regs, reads don't touch LDS region). Gate: vmcnt(2)@P1-top drains A(T),
// B(T) (leaves A(T+1)); per-tile issue order A then B matches prologue {A0,B0,A1}.
__global__ __launch_bounds__(512, 2) void gemm128(const unsigned short* __restrict__ A,
                                                  const unsigned short* __restrict__ B,
                                                  float* __restrict__ Cout) {
  extern __shared__ char smem[];   // 2 x 49152 B
  const int tid = threadIdx.x;
  const int w = tid >> 6, lane = tid & 63;
  const int quad = lane >> 4, l15 = lane & 15;
  const int wm = w >> 2, wn = w & 3;
  const int m0 = blockIdx.x * 128, n0 = blockIdx.y * 256;

  const int fragOff = l15 * 64 + ((quad * 16) ^ ((l15 & 8) << 2));
  char* const aWave = smem;                              // + dbuf*49152
  char* const bWave = smem + 16384 + (wn >> 1) * 16384;

  const int sr = lane >> 2;
  const int sc = ((lane & 3) * 8) ^ ((lane & 32) ? 16 : 0);   // bf16 col, pre-swizzled
  const unsigned short* const Abase = A + (size_t)(m0 + (w >> 1) * 16 + sr) * 2048 + (w & 1) * 32 + sc;
  const unsigned short* const Bbase = B + (size_t)(n0 + (w >> 1) * 16 + sr) * 2048 + (w & 1) * 32 + sc;

#define BARF()                            \
  asm volatile("" ::: "memory");          \
  __builtin_amdgcn_s_barrier();           \
  asm volatile("" ::: "memory");

#define G_STAGE_A(tt)                                                                    \
  {                                                                                      \
    const int t_ = ((tt) < 32) ? (tt) : 31;                                              \
    char* const d_ = smem + (t_ & 1) * 49152 + w * 1024;                                 \
    glds16(Abase + (size_t)t_ * 64, d_);                                                 \
    glds16(Abase + (64 * 2048) + (size_t)t_ * 64, d_ + 8192);                            \
  }
#define G_STAGE_B(h, tt)                                                                 \
  {                                                                                      \
    const int t_ = ((tt) < 32) ? (tt) : 31;                                              \
    char* const d_ = smem + (t_ & 1) * 49152 + 16384 + (h) * 16384 + w * 1024;           \
    glds16(Bbase + (size_t)(h) * (128 * 2048) + (size_t)t_ * 64, d_);                    \
    glds16(Bbase + (size_t)(h) * (128 * 2048) + (64 * 2048) + (size_t)t_ * 64, d_ + 8192); \
  }
#define G_RD_A(c)                                                                        \
  _Pragma("unroll") for (int mi = 0; mi < 4; ++mi)                                       \
  _Pragma("unroll") for (int kk = 0; kk < 2; ++kk)                                       \
      af[mi][kk] = *(const short8*)(aWave + (c) * 49152 + ((wm * 4 + mi) * 2 + kk) * 1024 + fragOff);
#define G_RD_B(dst, c, NI0)                                                              \
  _Pragma("unroll") for (int ni = 0; ni < 2; ++ni)                                       \
  _Pragma("unroll") for (int kk = 0; kk < 2; ++kk)                                       \
      dst[ni][kk] = *(const short8*)(bWave + (c) * 49152 + (((wn & 1) * 4 + (NI0) + ni) * 2 + kk) * 1024 + fragOff);

  f32x4 acc[4][4];
  const f32x4 fz = {0.f, 0.f, 0.f, 0.f};
#pragma unroll
  for (int i = 0; i < 4; ++i)
#pragma unroll
    for (int j = 0; j < 4; ++j) acc[i][j] = fz;

  short8 af[4][2], blo[2][2], bhi[2][2];

#define G_MFMA(NOFF, BF)                                                         \
  _Pragma("unroll") for (int kk = 0; kk < 2; ++kk)                               \
  _Pragma("unroll") for (int mi = 0; mi < 4; ++mi)                               \
  _Pragma("unroll") for (int ni = 0; ni < 2; ++ni)                               \
      acc[mi][(NOFF) + ni] = __builtin_amdgcn_mfma_f32_16x16x32_bf16(            \
          af[mi][kk], BF[ni][kk], acc[mi][(NOFF) + ni], 0, 0, 0);

  // prologue: A(0)x2, B(0)x4, A(1)x2; collective drain of tile0
  G_STAGE_A(0) G_STAGE_B(0, 0) G_STAGE_B(1, 0) G_STAGE_A(1)
  asm volatile("s_waitcnt vmcnt(2)" ::: "memory");
  BARF()

#define G_TILE(c, tt)                                                                \
  /* P1 */ asm volatile("s_waitcnt vmcnt(2)" ::: "memory");                          \
  G_RD_A(c) G_RD_B(blo, (c), 0)                                                      \
  G_STAGE_B(0, (tt) + 1) G_STAGE_B(1, (tt) + 1)                                      \
  BARF()                                                                             \
  __builtin_amdgcn_s_setprio(1); G_MFMA(0, blo) __builtin_amdgcn_s_setprio(0);       \
  BARF()                                                                             \
  /* P2 */ G_RD_B(bhi, (c), 2)                                                       \
  G_STAGE_A((tt) + 2)                                                                \
  BARF()                                                                             \
  __builtin_amdgcn_s_setprio(1); G_MFMA(2, bhi) __builtin_amdgcn_s_setprio(0);       \
  BARF()

#pragma unroll 1
  for (int T = 0; T < 32; T += 2) {
    G_TILE(0, T)
    G_TILE(1, T + 1)
  }
  asm volatile("s_waitcnt vmcnt(0)" ::: "memory");   // drain clamped tail rewrites
#undef G_TILE
#undef G_MFMA
#undef G_RD_A
#undef G_RD_B
#undef G_STAGE_A
#undef G_STAGE_B
#undef BARF

  const int colBase = n0 + wn * 64;
#pragma unroll
  for (int mi = 0; mi < 4; ++mi) {
    const int row = m0 + wm * 64 + mi * 16 + quad * 4;
#pragma unroll
    for (int ni = 0; ni < 4; ++ni) {
      const int col = colBase + ni * 16 + l15;
#pragma unroll
      for (int r = 0; r < 4; ++r)
        Cout[(size_t)(row + r) * 2048 + col] = acc[mi][ni][r];
    }
  }
}

// ------------------------------------------------------------ windowed GQA attention
// Block: 8 waves, 64 queries, one kv group. wave w: head g*4+(w&3), query-half w>>2.
__global__ __launch_bounds__(512) void attn_fwd(const unsigned short* __restrict__ qp,
                                                const unsigned short* __restrict__ kp,
                                                const unsigned short* __restrict__ vtg,
                                                unsigned short* __restrict__ op) {
  __shared__ unsigned short Ks[2][4][1024];   // [buf][kb][key*32+d']
  __shared__ unsigned short Vt[2][4096];      // [buf][d*32+key]
  const int tid = threadIdx.x;
  const int w = tid >> 6, lane = tid & 63;
  const int quad = lane >> 4, l15 = lane & 15;
  const int t0 = blockIdx.x * 64;
  const int g = blockIdx.y;
  const int h = g * 4 + (w & 3);
  const int t0w = t0 + (w >> 2) * 32;         // this wave's 32-query base
  const f32x4 fzero = {0.f, 0.f, 0.f, 0.f};
  const float scale = 0.088388347648318447f;  // 1/sqrt(128)
  const float NEG_INF = -__builtin_inff();

  short8 qf[4][2];
#pragma unroll
  for (int qt = 0; qt < 2; qt++) {
    const unsigned short* qrow = qp + (size_t)(t0w + qt * 16 + l15) * 2048 + h * 128 + quad * 8;
#pragma unroll
    for (int kb = 0; kb < 4; kb++) qf[kb][qt] = *(const short8*)(qrow + kb * 32);
  }

  f32x4 oacc[8][2];
#pragma unroll
  for (int db = 0; db < 8; db++) { oacc[db][0] = fzero; oacc[db][1] = fzero; }
  float Mrow[2] = {-1.0e30f, -1.0e30f}, Lrow[2] = {0.f, 0.f};

  const int s_begin = (t0 >= 512) ? (t0 - 512) : 0;
  const int nch = ((t0 + 63 - s_begin) >> 5) + 1;

  const int r4 = lane >> 2, c4 = lane & 3;
#define ATTN_STAGE(s0_, b_)                                                              \
  {                                                                                      \
    const int s0v = (s0_);                                                               \
    if (w < 4) {                                                                         \
      _Pragma("unroll")                                                                  \
      for (int p = 0; p < 2; p++)                                                        \
        glds16(kp + (size_t)(s0v + p * 16 + r4) * 512 + g * 128 + w * 32 + c4 * 8,       \
               &Ks[b_][w][p * 512]);                                                     \
    } else {                                                                             \
      const int wv = w - 4;                                                              \
      _Pragma("unroll")                                                                  \
      for (int p = 0; p < 2; p++)                                                        \
        glds16(vtg + (size_t)(g * 128 + wv * 32 + p * 16 + r4) * 4096 + s0v + c4 * 8,    \
               &Vt[b_][wv * 1024 + p * 512]);                                            \
    }                                                                                    \
  }

  ATTN_STAGE(s_begin, 0);

  for (int c = 0; c < nch; ++c) {
    const int s0 = s_begin + c * 32;
    const int b = c & 1;
    __syncthreads();                       // drain glds for chunk c (uniform)
    if (c + 1 < nch) ATTN_STAGE(s_begin + (c + 1) * 32, (c + 1) & 1);

    if (s0 + 31 >= t0w - 512 && s0 <= t0w + 31) {
      // ---- S^T = K * Q^T, permuted key rows
      f32x4 sacc[2][2];
      sacc[0][0] = fzero; sacc[0][1] = fzero; sacc[1][0] = fzero; sacc[1][1] = fzero;
      const int permBase = ((l15 >> 2) << 3) + (l15 & 3);   // + 4*kt
#pragma unroll
      for (int kb = 0; kb < 4; kb++) {
        short8 af0 = *(const short8*)&Ks[b][kb][(permBase + 0) * 32 + quad * 8];
        short8 af1 = *(const short8*)&Ks[b][kb][(permBase + 4) * 32 + quad * 8];
        sacc[0][0] = __builtin_amdgcn_mfma_f32_16x16x32_bf16(af0, qf[kb][0], sacc[0][0], 0, 0, 0);
        sacc[0][1] = __builtin_amdgcn_mfma_f32_16x16x32_bf16(af0, qf[kb][1], sacc[0][1], 0, 0, 0);
        sacc[1][0] = __builtin_amdgcn_mfma_f32_16x16x32_bf16(af1, qf[kb][0], sacc[1][0], 0, 0, 0);
        sacc[1][1] = __builtin_amdgcn_mfma_f32_16x16x32_bf16(af1, qf[kb][1], sacc[1][1], 0, 0, 0);
      }

      // ---- masked online softmax; key for (kt,r) = s0 + quad*8 + kt*4 + r
      short8 pb[2];
      float alpha[2];
#pragma unroll
      for (int qt = 0; qt < 2; qt++) {
        const int tq = t0w + qt * 16 + l15;
        float vals[8];
        float cmax = NEG_INF;
#pragma unroll
        for (int kt = 0; kt < 2; kt++)
#pragma unroll
          for (int r = 0; r < 4; r++) {
            const int s = s0 + quad * 8 + kt * 4 + r;
            const bool ok = (unsigned)(tq - s) <= 512u;
            const float v = ok ? sacc[kt][qt][r] * scale : NEG_INF;
            vals[kt * 4 + r] = v;
            cmax = fmaxf(cmax, v);
          }
        cmax = fmaxf(cmax, __shfl_xor(cmax, 16));
        cmax = fmaxf(cmax, __shfl_xor(cmax, 32));
        const float Mnew = fmaxf(Mrow[qt], cmax);
        alpha[qt] = __expf(Mrow[qt] - Mnew);
        Mrow[qt] = Mnew;
        float csum = 0.f;
#pragma unroll
        for (int j = 0; j < 8; j++) {
          const float p = __expf(vals[j] - Mnew);
          csum += p;
          pb[qt][j] = (short)f2b(p);
        }
        csum += __shfl_xor(csum, 16);
        csum += __shfl_xor(csum, 32);
        Lrow[qt] = Lrow[qt] * alpha[qt] + csum;
      }

      // ---- O^T += V^T * P^T
#pragma unroll
      for (int db = 0; db < 8; db++) {
        short8 vf = *(const short8*)&Vt[b][(db * 16 + l15) * 32 + quad * 8];
#pragma unroll
        for (int qt = 0; qt < 2; qt++) {
          oacc[db][qt][0] *= alpha[qt]; oacc[db][qt][1] *= alpha[qt];
          oacc[db][qt][2] *= alpha[qt]; oacc[db][qt][3] *= alpha[qt];
          oacc[db][qt] = __builtin_amdgcn_mfma_f32_16x16x32_bf16(vf, pb[qt], oacc[db][qt], 0, 0, 0);
        }
      }
    }
  }
#undef ATTN_STAGE

#pragma unroll
  for (int qt = 0; qt < 2; qt++) {
    const float invL = 1.f / Lrow[qt];
    unsigned short* orow = op + (size_t)(t0w + qt * 16 + l15) * 2048 + h * 128;
#pragma unroll
    for (int db = 0; db < 8; db++) {
      u16x4 o;
#pragma unroll
      for (int r = 0; r < 4; r++) o[r] = f2b(oacc[db][qt][r] * invL);
      *(u16x4*)(orow + db * 16 + quad * 4) = o;
    }
  }
}

// ---------------------------------------------------------------- launch
extern "C" void kernel_launch(void* const* d_in, const int* in_sizes, int n_in,
                              void* d_out, int out_size, void* d_ws, size_t ws_size,
                              hipStream_t stream) {
  const float* x  = (const float*)d_in[0];
  const float* wq = (const float*)d_in[1];
  const float* wk = (const float*)d_in[2];
  const float* wv = (const float*)d_in[3];
  const float* wo = (const float*)d_in[4];
  float* out = (float*)d_out;
  char* ws = (char*)d_ws;

  // workspace map (~63 MB); attnb aliases xb (dead after gemm256 qkv)
  unsigned short* xb    = (unsigned short*)(ws + 0);           // 16,777,216 B
  unsigned short* wqkv  = (unsigned short*)(ws + 16777216);    // 12,582,912 B
  unsigned short* wob   = (unsigned short*)(ws + 29360128);    //  8,388,608 B
  unsigned short* qb    = (unsigned short*)(ws + 37748736);    // 16,777,216 B
  unsigned short* kbuf  = (unsigned short*)(ws + 54525952);    //  4,194,304 B
  unsigned short* vtg   = (unsigned short*)(ws + 58720256);    //  4,194,304 B
  unsigned short* attnb = xb;

  static bool attr_done = false;
  if (!attr_done) {   // allow big dynamic LDS (host-side, not stream-ordered)
    hipFuncSetAttribute(reinterpret_cast<const void*>(gemm256),
                        hipFuncAttributeMaxDynamicSharedMemorySize, 131072);
    hipFuncSetAttribute(reinterpret_cast<const void*>(gemm128),
                        hipFuncAttributeMaxDynamicSharedMemorySize, 98304);
    attr_done = true;
  }

  cast_all<<<18432, 256, 0, stream>>>(x, wq, wk, wv, wo, (unsigned short*)ws);

  // qkv proj + fused RoPE + fused V-transpose (256^2 m201-shape 8-phase; N=3072)
  gemm256<<<dim3(16, 12), 512, 131072, stream>>>(xb, wqkv, 2048, 1,
                                                 qb, kbuf, vtg, nullptr, 0);

  attn_fwd<<<dim3(64, 4), 512, 0, stream>>>(qb, kbuf, vtg, attnb);

  // out = attn @ wo^T  (4096 x 2048, K=2048), fp32 out — 128x256 tiles, 256 blocks
  gemm128<<<dim3(32, 8), 512, 98304, stream>>>(attnb, wob, out);
}

// Round 6
// 242.869 us; speedup vs baseline: 1.1720x; 1.0070x over previous
//
#include <hip/hip_runtime.h>

typedef __attribute__((ext_vector_type(8))) short short8;
typedef __attribute__((ext_vector_type(4))) float f32x4;
typedef __attribute__((ext_vector_type(4))) unsigned short u16x4;

__device__ __forceinline__ unsigned short f2b(float f) {
  unsigned int u = __float_as_uint(f);
  u += 0x7fffu + ((u >> 16) & 1u);   // RNE
  return (unsigned short)(u >> 16);
}
__device__ __forceinline__ void glds16(const void* g, void* l) {
  __builtin_amdgcn_global_load_lds(
      (const __attribute__((address_space(1))) unsigned int*)g,
      (__attribute__((address_space(3))) unsigned int*)l, 16, 0, 0);
}

// ------------------------------------------------- fused cast: all 5 inputs -> bf16
__global__ __launch_bounds__(256) void cast_all(const float* __restrict__ x,
                                                const float* __restrict__ wq,
                                                const float* __restrict__ wk,
                                                const float* __restrict__ wv,
                                                const float* __restrict__ wo,
                                                unsigned short* __restrict__ dst) {
  const int i = blockIdx.x * 256 + threadIdx.x;   // < 4,718,592 (grid exact)
  const float* s;
  int off;
  if (i < 2097152)      { s = x;  off = i; }
  else if (i < 3145728) { s = wq; off = i - 2097152; }
  else if (i < 3407872) { s = wk; off = i - 3145728; }
  else if (i < 3670016) { s = wv; off = i - 3407872; }
  else                  { s = wo; off = i - 3670016; }
  f32x4 v = ((const f32x4*)s)[off];
  u16x4 o;
  o[0] = f2b(v[0]); o[1] = f2b(v[1]); o[2] = f2b(v[2]); o[3] = f2b(v[3]);
  ((u16x4*)dst)[i] = o;
}

// ------------------------------------------------------------------ 256x256 8-phase GEMM
// C = A * B^T, BM=BN=256, BK=64 (K=2048, 32 tiles), 8 waves (2Mx4N), 512 threads,
// 128 KiB LDS. Swizzled 16x32-subtile layout (pre-swizzled global src, linear glds).
//
// Schedule = round-3/4 read-ahead (measured 66 µs; the round-5 reads-at-top shape
// regressed to 81 µs on this 4-phase kernel — lgkm drain of 12 ds_reads landed on
// the MFMA cluster head with only 1 barrier of slack). Reads issue AFTER the MFMA
// cluster -> 2 barriers + a stage phase of slack before their consuming MFMA:
//   P1:                       | BAR | MFMA Q1(af=Alo,blo) | rd bhi(T)   | BAR
//   P2: stage Aj0(T+2) x2     | BAR | MFMA Q2(af,bhi)     | rd af<-Ahi(T)| BAR
//   P3: stage B(T+2) x4       | BAR | MFMA Q3(af,bhi)     |             | BAR
//   P4: stage Aj1(T+2) x2     | BAR | MFMA Q4(af,blo) | vmcnt(8) | rd af,blo(T+1)
// ONLY change vs round 4: MFMA_Q loop order is kk-OUTER — adjacent MFMAs are
// independent (the (mi,ni,kk) order made RAW-chained pairs on the same acc);
// per-acc kk order preserved -> bit-identical accumulation.
// WAR proofs and vmcnt(8) induction: see round-3 comments (unchanged).
// mode=1 (qkv): B n-block read permuted (nb) so ni=2j/2j+1 hold rope partners
// (d,d+64) -> thread-local RoPE epilogue. mode=0: plain fp32 C.
__global__ __launch_bounds__(512, 2) void gemm256(
    const unsigned short* __restrict__ A, const unsigned short* __restrict__ B,
    const int Karg, const int mode,
    unsigned short* __restrict__ qb, unsigned short* __restrict__ kb,
    unsigned short* __restrict__ vtg, float* __restrict__ Cout, const int Narg) {
  extern __shared__ char smem[];   // [2 dbuf][A:2x16K | B:2x16K] = 131072 B
  const int tid = threadIdx.x;
  const int w = tid >> 6, lane = tid & 63;
  const int quad = lane >> 4, l15 = lane & 15;
  const int wm = w >> 2, wn = w & 3;
  const int m0 = blockIdx.x * 256, n0 = blockIdx.y * 256;

  int nb[4];
#pragma unroll
  for (int ni = 0; ni < 4; ++ni) {
    const int bbi = (wn & 1) * 4 + ni;
    nb[ni] = mode ? ((bbi & 1) ? 4 + (bbi >> 1) : (bbi >> 1)) : bbi;
  }

  const int fragOff = l15 * 64 + ((quad * 16) ^ ((l15 & 8) << 2));
  char* const aWave = smem + wm * 16384;               // + dbuf*65536
  char* const bWave = smem + 32768 + (wn >> 1) * 16384;

  const int sr = lane >> 2;
  const int sc = ((lane & 3) * 8) ^ ((lane & 32) ? 16 : 0);   // bf16 col, pre-swizzled
  const unsigned short* const Abase = A + (size_t)(m0 + (w >> 1) * 16 + sr) * 2048 + (w & 1) * 32 + sc;
  const unsigned short* const Bbase = B + (size_t)(n0 + (w >> 1) * 16 + sr) * 2048 + (w & 1) * 32 + sc;

#define BARF()                            \
  asm volatile("" ::: "memory");          \
  __builtin_amdgcn_s_barrier();           \
  asm volatile("" ::: "memory");

#define STAGE_AJ(h, tt, jj)                                                              \
  {                                                                                      \
    const int t_ = ((tt) < 32) ? (tt) : 31;                                              \
    glds16(Abase + (size_t)(h) * (128 * 2048) + (jj) * (64 * 2048) + (size_t)t_ * 64,    \
           smem + (t_ & 1) * 65536 + (h) * 16384 + (jj) * 8192 + w * 1024);              \
  }
#define STAGE_B2(h, tt)                                                                  \
  {                                                                                      \
    const int t_ = ((tt) < 32) ? (tt) : 31;                                              \
    char* const d_ = smem + (t_ & 1) * 65536 + 32768 + (h) * 16384 + w * 1024;           \
    glds16(Bbase + (size_t)(h) * (128 * 2048) + (size_t)t_ * 64, d_);                    \
    glds16(Bbase + (size_t)(h) * (128 * 2048) + (64 * 2048) + (size_t)t_ * 64, d_ + 8192); \
  }
#define RD_A(dst, c, MI0)                                                                \
  _Pragma("unroll") for (int mi = 0; mi < 4; ++mi)                                       \
  _Pragma("unroll") for (int kk = 0; kk < 2; ++kk)                                       \
      dst[mi][kk] = *(const short8*)(aWave + (c) * 65536 + (((MI0) + mi) * 2 + kk) * 1024 + fragOff);
#define RD_B(dst, c, NI0)                                                                \
  _Pragma("unroll") for (int ni = 0; ni < 2; ++ni)                                       \
  _Pragma("unroll") for (int kk = 0; kk < 2; ++kk)                                       \
      dst[ni][kk] = *(const short8*)(bWave + (c) * 65536 + (nb[(NI0) + ni] * 2 + kk) * 1024 + fragOff);

  f32x4 acc[8][4];
  const f32x4 fz = {0.f, 0.f, 0.f, 0.f};
#pragma unroll
  for (int i = 0; i < 8; ++i)
#pragma unroll
    for (int j = 0; j < 4; ++j) acc[i][j] = fz;

  short8 af[4][2], blo[2][2], bhi[2][2];

  // kk-OUTER: adjacent MFMAs independent; per-acc kk order preserved (bit-identical)
#define MFMA_Q(MOFF, NOFF, BF)                                                   \
  _Pragma("unroll") for (int kk = 0; kk < 2; ++kk)                               \
  _Pragma("unroll") for (int mi = 0; mi < 4; ++mi)                               \
  _Pragma("unroll") for (int ni = 0; ni < 2; ++ni)                               \
      acc[(MOFF) + mi][(NOFF) + ni] = __builtin_amdgcn_mfma_f32_16x16x32_bf16(   \
          af[mi][kk], BF[ni][kk], acc[(MOFF) + mi][(NOFF) + ni], 0, 0, 0);

  // prologue: tile0 (8 glds) then tile1 (8 glds), per-tile unit order; collective drain
  STAGE_AJ(0, 0, 0) STAGE_AJ(1, 0, 0) STAGE_B2(0, 0) STAGE_B2(1, 0) STAGE_AJ(0, 0, 1) STAGE_AJ(1, 0, 1)
  STAGE_AJ(0, 1, 0) STAGE_AJ(1, 1, 0) STAGE_B2(0, 1) STAGE_B2(1, 1) STAGE_AJ(0, 1, 1) STAGE_AJ(1, 1, 1)
  asm volatile("s_waitcnt vmcnt(8)" ::: "memory");   // tile0 resident; tile1 in flight
  __builtin_amdgcn_s_barrier();
  asm volatile("" ::: "memory");
  RD_A(af, 0, 0)    // Alo(0)
  RD_B(blo, 0, 0)   // Blo(0)

#define HALF(c, tt)                                                                  \
  /* P1 */                                                                           \
  BARF()                                                                             \
  __builtin_amdgcn_s_setprio(1); MFMA_Q(0, 0, blo) __builtin_amdgcn_s_setprio(0);    \
  RD_B(bhi, (c), 2)                                                                  \
  BARF()                                                                             \
  /* P2 */ STAGE_AJ(0, (tt) + 2, 0) STAGE_AJ(1, (tt) + 2, 0)                         \
  BARF()                                                                             \
  __builtin_amdgcn_s_setprio(1); MFMA_Q(0, 2, bhi) __builtin_amdgcn_s_setprio(0);    \
  RD_A(af, (c), 4)                                                                   \
  BARF()                                                                             \
  /* P3 */ STAGE_B2(0, (tt) + 2) STAGE_B2(1, (tt) + 2)                               \
  BARF()                                                                             \
  __builtin_amdgcn_s_setprio(1); MFMA_Q(4, 2, bhi) __builtin_amdgcn_s_setprio(0);    \
  BARF()                                                                             \
  /* P4 */ STAGE_AJ(0, (tt) + 2, 1) STAGE_AJ(1, (tt) + 2, 1)                         \
  BARF()                                                                             \
  __builtin_amdgcn_s_setprio(1); MFMA_Q(4, 0, blo) __builtin_amdgcn_s_setprio(0);    \
  asm volatile("s_waitcnt vmcnt(8)" ::: "memory");                                   \
  RD_A(af, (c) ^ 1, 0)                                                               \
  RD_B(blo, (c) ^ 1, 0)

#pragma unroll 1
  for (int T = 0; T < 32; T += 2) {
    HALF(0, T)
    HALF(1, T + 1)
  }
  asm volatile("s_waitcnt vmcnt(0)" ::: "memory");   // drain clamped tail rewrites
#undef HALF
#undef MFMA_Q
#undef RD_A
#undef RD_B
#undef STAGE_AJ
#undef STAGE_B2
#undef BARF

  // ------------------------------------------------------------------ epilogues
  if (mode == 0) {
    const int colBase = n0 + wn * 64;
#pragma unroll
    for (int mi = 0; mi < 8; ++mi) {
      const int row = m0 + wm * 128 + mi * 16 + quad * 4;
#pragma unroll
      for (int ni = 0; ni < 4; ++ni) {
        const int col = colBase + ni * 16 + l15;
#pragma unroll
        for (int r = 0; r < 4; ++r)
          Cout[(size_t)(row + r) * 2048 + col] = acc[mi][ni][r];
      }
    }
    return;
  }

  const int y = blockIdx.y;            // 0-7: Q heads 2y,2y+1 | 8-9: K | 10-11: V
  const int tb0 = m0 + wm * 128;
  if (y >= 10) {
    const int g = (y - 10) * 2 + (wn >> 1);
#pragma unroll
    for (int mi = 0; mi < 8; ++mi) {
      const int tb = tb0 + mi * 16 + quad * 4;
#pragma unroll
      for (int ni = 0; ni < 4; ++ni) {
        const int d = nb[ni] * 16 + l15;
        u16x4 o;
#pragma unroll
        for (int r = 0; r < 4; ++r) o[r] = f2b(acc[mi][ni][r]);
        *(u16x4*)(vtg + (size_t)(g * 128 + d) * 4096 + tb) = o;
      }
    }
  } else {
    unsigned short* dst;
    int stride, hoff;
    if (y < 8) { dst = qb; stride = 2048; hoff = (y * 2 + (wn >> 1)) * 128; }
    else       { dst = kb; stride = 512;  hoff = ((y - 8) * 2 + (wn >> 1)) * 128; }
    const float c2 = 0.20762050593045889f;   // log2(10000)/64
    const float inv2pi = 0.15915494309189535f;
#pragma unroll
    for (int j = 0; j < 2; ++j) {
      const int i = ((wn & 1) * 2 + j) * 16 + l15;            // rope dim, < 64
      const float inv_rev = exp2f(-(float)i * c2) * inv2pi;   // freq in revolutions
#pragma unroll
      for (int mi = 0; mi < 8; ++mi) {
#pragma unroll
        for (int r = 0; r < 4; ++r) {
          const int t = tb0 + mi * 16 + quad * 4 + r;
          float rev = (float)t * inv_rev;
          rev -= floorf(rev);                    // [0,1) for HW v_sin/v_cos
          const float sn = __builtin_amdgcn_sinf(rev);
          const float cs = __builtin_amdgcn_cosf(rev);
          const float x1 = acc[mi][2 * j][r], x2 = acc[mi][2 * j + 1][r];
          unsigned short* p = dst + (size_t)t * stride + hoff + i;
          p[0]  = f2b(x1 * cs - x2 * sn);
          p[64] = f2b(x1 * sn + x2 * cs);
        }
      }
    }
  }
}

// ------------------------------------------------------------------ 128x256 2-phase GEMM
// C = A * B^T fp32 (wo projection). Grid (32,8) = 256 blocks = full chip.
// Reads-at-top + kk-outer (round-5 form — measured best for this 2-phase kernel):
//   P1: vmcnt(2) | rd af(T), blo(T) | stage B(T+1) x4 | BAR | MFMA n-lo | BAR
//   P2:          | rd bhi(T)        | stage A(T+2) x2 | BAR | MFMA n-hi | BAR
__global__ __launch_bounds__(512, 2) void gemm128(const unsigned short* __restrict__ A,
                                                  const unsigned short* __restrict__ B,
                                                  float* __restrict__ Cout) {
  extern __shared__ char smem[];   // 2 x 49152 B
  const int tid = threadIdx.x;
  const int w = tid >> 6, lane = tid & 63;
  const int quad = lane >> 4, l15 = lane & 15;
  const int wm = w >> 2, wn = w & 3;
  const int m0 = blockIdx.x * 128, n0 = blockIdx.y * 256;

  const int fragOff = l15 * 64 + ((quad * 16) ^ ((l15 & 8) << 2));
  char* const aWave = smem;                              // + dbuf*49152
  char* const bWave = smem + 16384 + (wn >> 1) * 16384;

  const int sr = lane >> 2;
  const int sc = ((lane & 3) * 8) ^ ((lane & 32) ? 16 : 0);   // bf16 col, pre-swizzled
  const unsigned short* const Abase = A + (size_t)(m0 + (w >> 1) * 16 + sr) * 2048 + (w & 1) * 32 + sc;
  const unsigned short* const Bbase = B + (size_t)(n0 + (w >> 1) * 16 + sr) * 2048 + (w & 1) * 32 + sc;

#define BARF()                            \
  asm volatile("" ::: "memory");          \
  __builtin_amdgcn_s_barrier();           \
  asm volatile("" ::: "memory");

#define G_STAGE_A(tt)                                                                    \
  {                                                                                      \
    const int t_ = ((tt) < 32) ? (tt) : 31;                                              \
    char* const d_ = smem + (t_ & 1) * 49152 + w * 1024;                                 \
    glds16(Abase + (size_t)t_ * 64, d_);                                                 \
    glds16(Abase + (64 * 2048) + (size_t)t_ * 64, d_ + 8192);                            \
  }
#define G_STAGE_B(h, tt)                                                                 \
  {                                                                                      \
    const int t_ = ((tt) < 32) ? (tt) : 31;                                              \
    char* const d_ = smem + (t_ & 1) * 49152 + 16384 + (h) * 16384 + w * 1024;           \
    glds16(Bbase + (size_t)(h) * (128 * 2048) + (size_t)t_ * 64, d_);                    \
    glds16(Bbase + (size_t)(h) * (128 * 2048) + (64 * 2048) + (size_t)t_ * 64, d_ + 8192); \
  }
#define G_RD_A(c)                                                                        \
  _Pragma("unroll") for (int mi = 0; mi < 4; ++mi)                                       \
  _Pragma("unroll") for (int kk = 0; kk < 2; ++kk)                                       \
      af[mi][kk] = *(const short8*)(aWave + (c) * 49152 + ((wm * 4 + mi) * 2 + kk) * 1024 + fragOff);
#define G_RD_B(dst, c, NI0)                                                              \
  _Pragma("unroll") for (int ni = 0; ni < 2; ++ni)                                       \
  _Pragma("unroll") for (int kk = 0; kk < 2; ++kk)                                       \
      dst[ni][kk] = *(const short8*)(bWave + (c) * 49152 + (((wn & 1) * 4 + (NI0) + ni) * 2 + kk) * 1024 + fragOff);

  f32x4 acc[4][4];
  const f32x4 fz = {0.f, 0.f, 0.f, 0.f};
#pragma unroll
  for (int i = 0; i < 4; ++i)
#pragma unroll
    for (int j = 0; j < 4; ++j) acc[i][j] = fz;

  short8 af[4][2], blo[2][2], bhi[2][2];

#define G_MFMA(NOFF, BF)                                                         \
  _Pragma("unroll") for (int kk = 0; kk < 2; ++kk)                               \
  _Pragma("unroll") for (int mi = 0; mi < 4; ++mi)                               \
  _Pragma("unroll") for (int ni = 0; ni < 2; ++ni)                               \
      acc[mi][(NOFF) + ni] = __builtin_amdgcn_mfma_f32_16x16x32_bf16(            \
          af[mi][kk], BF[ni][kk], acc[mi][(NOFF) + ni], 0, 0, 0);

  // prologue: A(0)x2, B(0)x4, A(1)x2; collective drain of tile0
  G_STAGE_A(0) G_STAGE_B(0, 0) G_STAGE_B(1, 0) G_STAGE_A(1)
  asm volatile("s_waitcnt vmcnt(2)" ::: "memory");
  BARF()

#define G_TILE(c, tt)                                                                \
  /* P1 */ asm volatile("s_waitcnt vmcnt(2)" ::: "memory");                          \
  G_RD_A(c) G_RD_B(blo, (c), 0)                                                      \
  G_STAGE_B(0, (tt) + 1) G_STAGE_B(1, (tt) + 1)                                      \
  BARF()                                                                             \
  __builtin_amdgcn_s_setprio(1); G_MFMA(0, blo) __builtin_amdgcn_s_setprio(0);       \
  BARF()                                                                             \
  /* P2 */ G_RD_B(bhi, (c), 2)                                                       \
  G_STAGE_A((tt) + 2)                                                                \
  BARF()                                                                             \
  __builtin_amdgcn_s_setprio(1); G_MFMA(2, bhi) __builtin_amdgcn_s_setprio(0);       \
  BARF()

#pragma unroll 1
  for (int T = 0; T < 32; T += 2) {
    G_TILE(0, T)
    G_TILE(1, T + 1)
  }
  asm volatile("s_waitcnt vmcnt(0)" ::: "memory");   // drain clamped tail rewrites
#undef G_TILE
#undef G_MFMA
#undef G_RD_A
#undef G_RD_B
#undef G_STAGE_A
#undef G_STAGE_B
#undef BARF

  const int colBase = n0 + wn * 64;
#pragma unroll
  for (int mi = 0; mi < 4; ++mi) {
    const int row = m0 + wm * 64 + mi * 16 + quad * 4;
#pragma unroll
    for (int ni = 0; ni < 4; ++ni) {
      const int col = colBase + ni * 16 + l15;
#pragma unroll
      for (int r = 0; r < 4; ++r)
        Cout[(size_t)(row + r) * 2048 + col] = acc[mi][ni][r];
    }
  }
}

// ------------------------------------------------------------ windowed GQA attention
// Block: 8 waves, 64 queries, one kv group. wave w: head g*4+(w&3), query-half w>>2.
__global__ __launch_bounds__(512) void attn_fwd(const unsigned short* __restrict__ qp,
                                                const unsigned short* __restrict__ kp,
                                                const unsigned short* __restrict__ vtg,
                                                unsigned short* __restrict__ op) {
  __shared__ unsigned short Ks[2][4][1024];   // [buf][kb][key*32+d']
  __shared__ unsigned short Vt[2][4096];      // [buf][d*32+key]
  const int tid = threadIdx.x;
  const int w = tid >> 6, lane = tid & 63;
  const int quad = lane >> 4, l15 = lane & 15;
  const int t0 = blockIdx.x * 64;
  const int g = blockIdx.y;
  const int h = g * 4 + (w & 3);
  const int t0w = t0 + (w >> 2) * 32;         // this wave's 32-query base
  const f32x4 fzero = {0.f, 0.f, 0.f, 0.f};
  const float scale = 0.088388347648318447f;  // 1/sqrt(128)
  const float NEG_INF = -__builtin_inff();

  short8 qf[4][2];
#pragma unroll
  for (int qt = 0; qt < 2; qt++) {
    const unsigned short* qrow = qp + (size_t)(t0w + qt * 16 + l15) * 2048 + h * 128 + quad * 8;
#pragma unroll
    for (int kb = 0; kb < 4; kb++) qf[kb][qt] = *(const short8*)(qrow + kb * 32);
  }

  f32x4 oacc[8][2];
#pragma unroll
  for (int db = 0; db < 8; db++) { oacc[db][0] = fzero; oacc[db][1] = fzero; }
  float Mrow[2] = {-1.0e30f, -1.0e30f}, Lrow[2] = {0.f, 0.f};

  const int s_begin = (t0 >= 512) ? (t0 - 512) : 0;
  const int nch = ((t0 + 63 - s_begin) >> 5) + 1;

  const int r4 = lane >> 2, c4 = lane & 3;
#define ATTN_STAGE(s0_, b_)                                                              \
  {                                                                                      \
    const int s0v = (s0_);                                                               \
    if (w < 4) {                                                                         \
      _Pragma("unroll")                                                                  \
      for (int p = 0; p < 2; p++)                                                        \
        glds16(kp + (size_t)(s0v + p * 16 + r4) * 512 + g * 128 + w * 32 + c4 * 8,       \
               &Ks[b_][w][p * 512]);                                                     \
    } else {                                                                             \
      const int wv = w - 4;                                                              \
      _Pragma("unroll")                                                                  \
      for (int p = 0; p < 2; p++)                                                        \
        glds16(vtg + (size_t)(g * 128 + wv * 32 + p * 16 + r4) * 4096 + s0v + c4 * 8,    \
               &Vt[b_][wv * 1024 + p * 512]);                                            \
    }                                                                                    \
  }

  ATTN_STAGE(s_begin, 0);

  for (int c = 0; c < nch; ++c) {
    const int s0 = s_begin + c * 32;
    const int b = c & 1;
    __syncthreads();                       // drain glds for chunk c (uniform)
    if (c + 1 < nch) ATTN_STAGE(s_begin + (c + 1) * 32, (c + 1) & 1);

    if (s0 + 31 >= t0w - 512 && s0 <= t0w + 31) {
      // ---- S^T = K * Q^T, permuted key rows
      f32x4 sacc[2][2];
      sacc[0][0] = fzero; sacc[0][1] = fzero; sacc[1][0] = fzero; sacc[1][1] = fzero;
      const int permBase = ((l15 >> 2) << 3) + (l15 & 3);   // + 4*kt
#pragma unroll
      for (int kb = 0; kb < 4; kb++) {
        short8 af0 = *(const short8*)&Ks[b][kb][(permBase + 0) * 32 + quad * 8];
        short8 af1 = *(const short8*)&Ks[b][kb][(permBase + 4) * 32 + quad * 8];
        sacc[0][0] = __builtin_amdgcn_mfma_f32_16x16x32_bf16(af0, qf[kb][0], sacc[0][0], 0, 0, 0);
        sacc[0][1] = __builtin_amdgcn_mfma_f32_16x16x32_bf16(af0, qf[kb][1], sacc[0][1], 0, 0, 0);
        sacc[1][0] = __builtin_amdgcn_mfma_f32_16x16x32_bf16(af1, qf[kb][0], sacc[1][0], 0, 0, 0);
        sacc[1][1] = __builtin_amdgcn_mfma_f32_16x16x32_bf16(af1, qf[kb][1], sacc[1][1], 0, 0, 0);
      }

      // ---- masked online softmax; key for (kt,r) = s0 + quad*8 + kt*4 + r
      short8 pb[2];
      float alpha[2];
#pragma unroll
      for (int qt = 0; qt < 2; qt++) {
        const int tq = t0w + qt * 16 + l15;
        float vals[8];
        float cmax = NEG_INF;
#pragma unroll
        for (int kt = 0; kt < 2; kt++)
#pragma unroll
          for (int r = 0; r < 4; r++) {
            const int s = s0 + quad * 8 + kt * 4 + r;
            const bool ok = (unsigned)(tq - s) <= 512u;
            const float v = ok ? sacc[kt][qt][r] * scale : NEG_INF;
            vals[kt * 4 + r] = v;
            cmax = fmaxf(cmax, v);
          }
        cmax = fmaxf(cmax, __shfl_xor(cmax, 16));
        cmax = fmaxf(cmax, __shfl_xor(cmax, 32));
        const float Mnew = fmaxf(Mrow[qt], cmax);
        alpha[qt] = __expf(Mrow[qt] - Mnew);
        Mrow[qt] = Mnew;
        float csum = 0.f;
#pragma unroll
        for (int j = 0; j < 8; j++) {
          const float p = __expf(vals[j] - Mnew);
          csum += p;
          pb[qt][j] = (short)f2b(p);
        }
        csum += __shfl_xor(csum, 16);
        csum += __shfl_xor(csum, 32);
        Lrow[qt] = Lrow[qt] * alpha[qt] + csum;
      }

      // ---- O^T += V^T * P^T
#pragma unroll
      for (int db = 0; db < 8; db++) {
        short8 vf = *(const short8*)&Vt[b][(db * 16 + l15) * 32 + quad * 8];
#pragma unroll
        for (int qt = 0; qt < 2; qt++) {
          oacc[db][qt][0] *= alpha[qt]; oacc[db][qt][1] *= alpha[qt];
          oacc[db][qt][2] *= alpha[qt]; oacc[db][qt][3] *= alpha[qt];
          oacc[db][qt] = __builtin_amdgcn_mfma_f32_16x16x32_bf16(vf, pb[qt], oacc[db][qt], 0, 0, 0);
        }
      }
    }
  }
#undef ATTN_STAGE

#pragma unroll
  for (int qt = 0; qt < 2; qt++) {
    const float invL = 1.f / Lrow[qt];
    unsigned short* orow = op + (size_t)(t0w + qt * 16 + l15) * 2048 + h * 128;
#pragma unroll
    for (int db = 0; db < 8; db++) {
      u16x4 o;
#pragma unroll
      for (int r = 0; r < 4; r++) o[r] = f2b(oacc[db][qt][r] * invL);
      *(u16x4*)(orow + db * 16 + quad * 4) = o;
    }
  }
}

// ---------------------------------------------------------------- launch
extern "C" void kernel_launch(void* const* d_in, const int* in_sizes, int n_in,
                              void* d_out, int out_size, void* d_ws, size_t ws_size,
                              hipStream_t stream) {
  const float* x  = (const float*)d_in[0];
  const float* wq = (const float*)d_in[1];
  const float* wk = (const float*)d_in[2];
  const float* wv = (const float*)d_in[3];
  const float* wo = (const float*)d_in[4];
  float* out = (float*)d_out;
  char* ws = (char*)d_ws;

  // workspace map (~63 MB); attnb aliases xb (dead after gemm256 qkv)
  unsigned short* xb    = (unsigned short*)(ws + 0);           // 16,777,216 B
  unsigned short* wqkv  = (unsigned short*)(ws + 16777216);    // 12,582,912 B
  unsigned short* wob   = (unsigned short*)(ws + 29360128);    //  8,388,608 B
  unsigned short* qb    = (unsigned short*)(ws + 37748736);    // 16,777,216 B
  unsigned short* kbuf  = (unsigned short*)(ws + 54525952);    //  4,194,304 B
  unsigned short* vtg   = (unsigned short*)(ws + 58720256);    //  4,194,304 B
  unsigned short* attnb = xb;

  static bool attr_done = false;
  if (!attr_done) {   // allow big dynamic LDS (host-side, not stream-ordered)
    hipFuncSetAttribute(reinterpret_cast<const void*>(gemm256),
                        hipFuncAttributeMaxDynamicSharedMemorySize, 131072);
    hipFuncSetAttribute(reinterpret_cast<const void*>(gemm128),
                        hipFuncAttributeMaxDynamicSharedMemorySize, 98304);
    attr_done = true;
  }

  cast_all<<<18432, 256, 0, stream>>>(x, wq, wk, wv, wo, (unsigned short*)ws);

  // qkv proj + fused RoPE + fused V-transpose (256^2 r4-schedule + kk-outer; N=3072)
  gemm256<<<dim3(16, 12), 512, 131072, stream>>>(xb, wqkv, 2048, 1,
                                                 qb, kbuf, vtg, nullptr, 0);

  attn_fwd<<<dim3(64, 4), 512, 0, stream>>>(qb, kbuf, vtg, attnb);

  // out = attn @ wo^T  (4096 x 2048, K=2048), fp32 out — 128x256 tiles, 256 blocks
  gemm128<<<dim3(32, 8), 512, 98304, stream>>>(attnb, wob, out);
}

// Round 7
// 238.850 us; speedup vs baseline: 1.1917x; 1.0168x over previous
//
#include <hip/hip_runtime.h>

typedef __attribute__((ext_vector_type(8))) short short8;
typedef __attribute__((ext_vector_type(4))) float f32x4;
typedef __attribute__((ext_vector_type(4))) unsigned short u16x4;

__device__ __forceinline__ unsigned short f2b(float f) {
  unsigned int u = __float_as_uint(f);
  u += 0x7fffu + ((u >> 16) & 1u);   // RNE
  return (unsigned short)(u >> 16);
}
__device__ __forceinline__ void glds16(const void* g, void* l) {
  __builtin_amdgcn_global_load_lds(
      (const __attribute__((address_space(1))) unsigned int*)g,
      (__attribute__((address_space(3))) unsigned int*)l, 16, 0, 0);
}

// ------------------------------------------------- fused cast: all 5 inputs -> bf16
__global__ __launch_bounds__(256) void cast_all(const float* __restrict__ x,
                                                const float* __restrict__ wq,
                                                const float* __restrict__ wk,
                                                const float* __restrict__ wv,
                                                const float* __restrict__ wo,
                                                unsigned short* __restrict__ dst) {
  const int i = blockIdx.x * 256 + threadIdx.x;   // < 4,718,592 (grid exact)
  const float* s;
  int off;
  if (i < 2097152)      { s = x;  off = i; }
  else if (i < 3145728) { s = wq; off = i - 2097152; }
  else if (i < 3407872) { s = wk; off = i - 3145728; }
  else if (i < 3670016) { s = wv; off = i - 3407872; }
  else                  { s = wo; off = i - 3670016; }
  f32x4 v = ((const f32x4*)s)[off];
  u16x4 o;
  o[0] = f2b(v[0]); o[1] = f2b(v[1]); o[2] = f2b(v[2]); o[3] = f2b(v[3]);
  ((u16x4*)dst)[i] = o;
}

#define BARF()                            \
  asm volatile("" ::: "memory");          \
  __builtin_amdgcn_s_barrier();           \
  asm volatile("" ::: "memory");

// ------------------------------------------------------------------ 128x128 2-phase GEMM
// qkv projection, CO-RESIDENT: BM=BN=128, BK=64 (K=2048, 32 tiles), 8 waves (2Mx4N),
// 64 KiB LDS -> 2 blocks/CU (cross-block overlap hides barrier/vmcnt stalls — the
// 1-resident gemm256 had every stall global). Grid (32,24) = 768 blocks = 3.0/CU.
// Per-wave 64x32 output, acc[4][2]; __launch_bounds__(512,4) caps VGPR at 128.
// LDS: [16] subtiles of 16x32 bf16 (1024 B) per operand, s = rb*2+kk (rb=row-block,
// kk=col-half); st_16x32 XOR swizzle via pre-swizzled global src (gemm128-proven).
// Phases per K-tile:
//   P1: rd af-hi | fence | rd af-lo,bf | stage B(T+1)->c^1 | BAR | MFMA mi-lo | BAR
//   P2: stage A(T+2)->c                | BAR | MFMA mi-hi | vmcnt(2) | BAR
// Soundness: (a) ds_reads ordered af-hi -> fence -> af-lo+bf; DS returns in-order, so
// the compiler's lgkm wait before P1's MFMA (covers bf, youngest) proves af-hi drained
// before P2-top's stage-A overwrites that region (>=1 barrier later, all waves).
// (b) vmcnt(2) gate sits BEFORE P2's closing barrier: gate->barrier->read means every
// wave's staging of tile T+1 is drained before ANY wave reads it (cross-wave sound;
// the old gate-at-read-top only gated the reading wave's own loads).
// Gate induction: end of P2(T) outstanding = [A(T+1),B(T+1),A(T+2)] = 6 glds ->
// vmcnt(2) drains A(T+1),B(T+1), leaves A(T+2). Prologue {A0,B0,A1; vmcnt(2); BAR}.
// Tail: staged index clamped to 31 (identical-byte rewrite, benign).
// mode=1: 1 head per 128-col tile; col-blocks cb={wn, wn+4} put rope partners
// (d, d+64) in acc[mi][0]/acc[mi][1] -> thread-local RoPE. y: 0-15 Q, 16-19 K,
// 20-23 V(transposed store). mode=0: plain fp32 C (cb={2wn, 2wn+1}).
__global__ __launch_bounds__(512, 4) void gemm_t128(
    const unsigned short* __restrict__ A, const unsigned short* __restrict__ B,
    const int mode,
    unsigned short* __restrict__ qb, unsigned short* __restrict__ kb,
    unsigned short* __restrict__ vtg, float* __restrict__ Cout) {
  extern __shared__ char smem[];   // 2 dbuf x [A 16K | B 16K] = 65536 B
  const int tid = threadIdx.x;
  const int w = tid >> 6, lane = tid & 63;
  const int quad = lane >> 4, l15 = lane & 15;
  const int wm = w >> 2, wn = w & 3;
  const int m0 = blockIdx.x * 128;
  const int y  = blockIdx.y;
  const int n0 = y * 128;

  int cb[2];
  cb[0] = mode ? wn : wn * 2;
  cb[1] = mode ? wn + 4 : wn * 2 + 1;

  const int fragOff = l15 * 64 + ((quad * 16) ^ ((l15 & 8) << 2));
  const int sr = lane >> 2;
  const int sc = ((lane & 3) * 8) ^ ((lane & 32) ? 16 : 0);   // bf16 col, pre-swizzled
  const unsigned short* const Abase = A + (size_t)(m0 + (w >> 1) * 16 + sr) * 2048 + (w & 1) * 32 + sc;
  const unsigned short* const Bbase = B + (size_t)(n0 + (w >> 1) * 16 + sr) * 2048 + (w & 1) * 32 + sc;

#define T_STAGE_A(tt)                                                                    \
  {                                                                                      \
    const int t_ = ((tt) < 32) ? (tt) : 31;                                              \
    char* const d_ = smem + (t_ & 1) * 32768 + w * 1024;                                 \
    glds16(Abase + (size_t)t_ * 64, d_);                                                 \
    glds16(Abase + (64 * 2048) + (size_t)t_ * 64, d_ + 8192);                            \
  }
#define T_STAGE_B(tt)                                                                    \
  {                                                                                      \
    const int t_ = ((tt) < 32) ? (tt) : 31;                                              \
    char* const d_ = smem + (t_ & 1) * 32768 + 16384 + w * 1024;                         \
    glds16(Bbase + (size_t)t_ * 64, d_);                                                 \
    glds16(Bbase + (64 * 2048) + (size_t)t_ * 64, d_ + 8192);                            \
  }
#define T_RD_AHI(c)                                                                      \
  _Pragma("unroll") for (int mi = 2; mi < 4; ++mi)                                       \
  _Pragma("unroll") for (int kk = 0; kk < 2; ++kk)                                       \
      af[mi][kk] = *(const short8*)(smem + (c) * 32768 + ((wm * 4 + mi) * 2 + kk) * 1024 + fragOff);
#define T_RD_ALO(c)                                                                      \
  _Pragma("unroll") for (int mi = 0; mi < 2; ++mi)                                       \
  _Pragma("unroll") for (int kk = 0; kk < 2; ++kk)                                       \
      af[mi][kk] = *(const short8*)(smem + (c) * 32768 + ((wm * 4 + mi) * 2 + kk) * 1024 + fragOff);
#define T_RD_B(c)                                                                        \
  _Pragma("unroll") for (int ni = 0; ni < 2; ++ni)                                       \
  _Pragma("unroll") for (int kk = 0; kk < 2; ++kk)                                       \
      bf[ni][kk] = *(const short8*)(smem + (c) * 32768 + 16384 + (cb[ni] * 2 + kk) * 1024 + fragOff);

  f32x4 acc[4][2];
  const f32x4 fz = {0.f, 0.f, 0.f, 0.f};
#pragma unroll
  for (int i = 0; i < 4; ++i) { acc[i][0] = fz; acc[i][1] = fz; }

  short8 af[4][2], bf[2][2];

#define T_MFMA(MI0)                                                              \
  _Pragma("unroll") for (int kk = 0; kk < 2; ++kk)                               \
  _Pragma("unroll") for (int mi = 0; mi < 2; ++mi)                               \
  _Pragma("unroll") for (int ni = 0; ni < 2; ++ni)                               \
      acc[(MI0) + mi][ni] = __builtin_amdgcn_mfma_f32_16x16x32_bf16(             \
          af[(MI0) + mi][kk], bf[ni][kk], acc[(MI0) + mi][ni], 0, 0, 0);

  // prologue: A(0), B(0), A(1); gate -> barrier (all waves' tile0 drained)
  T_STAGE_A(0) T_STAGE_B(0) T_STAGE_A(1)
  asm volatile("s_waitcnt vmcnt(2)" ::: "memory");
  BARF()

#define T_TILE(c, tt)                                                                \
  /* P1 */ T_RD_AHI(c)                                                               \
  asm volatile("" ::: "memory");                                                     \
  T_RD_ALO(c) T_RD_B(c)                                                              \
  T_STAGE_B((tt) + 1)                                                                \
  BARF()                                                                             \
  __builtin_amdgcn_s_setprio(1); T_MFMA(0) __builtin_amdgcn_s_setprio(0);            \
  BARF()                                                                             \
  /* P2 */ T_STAGE_A((tt) + 2)                                                       \
  BARF()                                                                             \
  __builtin_amdgcn_s_setprio(1); T_MFMA(2) __builtin_amdgcn_s_setprio(0);            \
  asm volatile("s_waitcnt vmcnt(2)" ::: "memory");                                   \
  BARF()

#pragma unroll 1
  for (int T = 0; T < 32; T += 2) {
    T_TILE(0, T)
    T_TILE(1, T + 1)
  }
  asm volatile("s_waitcnt vmcnt(0)" ::: "memory");   // drain clamped tail rewrites
#undef T_TILE
#undef T_MFMA
#undef T_RD_AHI
#undef T_RD_ALO
#undef T_RD_B
#undef T_STAGE_A
#undef T_STAGE_B

  // ------------------------------------------------------------------ epilogues
  const int tb0 = m0 + wm * 64;
  if (mode == 0) {
#pragma unroll
    for (int mi = 0; mi < 4; ++mi) {
      const int row = tb0 + mi * 16 + quad * 4;
#pragma unroll
      for (int ni = 0; ni < 2; ++ni) {
        const int col = n0 + cb[ni] * 16 + l15;
#pragma unroll
        for (int r = 0; r < 4; ++r)
          Cout[(size_t)(row + r) * 2048 + col] = acc[mi][ni][r];
      }
    }
    return;
  }
  if (y >= 20) {
    // ---- V: store transposed into vtg[g][d][t]
    const int g = y - 20;
#pragma unroll
    for (int mi = 0; mi < 4; ++mi) {
      const int tb = tb0 + mi * 16 + quad * 4;
#pragma unroll
      for (int ni = 0; ni < 2; ++ni) {
        const int d = cb[ni] * 16 + l15;                // wn*16 + l15 + 64*ni
        u16x4 o;
#pragma unroll
        for (int r = 0; r < 4; ++r) o[r] = f2b(acc[mi][ni][r]);
        *(u16x4*)(vtg + (size_t)(g * 128 + d) * 4096 + tb) = o;
      }
    }
  } else {
    // ---- Q/K: thread-local RoPE; acc[mi][0] = dim i, acc[mi][1] = dim i+64
    unsigned short* dst;
    int stride, hoff;
    if (y < 16) { dst = qb; stride = 2048; hoff = y * 128; }
    else        { dst = kb; stride = 512;  hoff = (y - 16) * 128; }
    const float c2 = 0.20762050593045889f;   // log2(10000)/64
    const float inv2pi = 0.15915494309189535f;
    const int i = wn * 16 + l15;                        // rope dim, < 64
    const float inv_rev = exp2f(-(float)i * c2) * inv2pi;
#pragma unroll
    for (int mi = 0; mi < 4; ++mi) {
#pragma unroll
      for (int r = 0; r < 4; ++r) {
        const int t = tb0 + mi * 16 + quad * 4 + r;
        float rev = (float)t * inv_rev;
        rev -= floorf(rev);                    // [0,1) for HW v_sin/v_cos
        const float sn = __builtin_amdgcn_sinf(rev);
        const float cs = __builtin_amdgcn_cosf(rev);
        const float x1 = acc[mi][0][r], x2 = acc[mi][1][r];
        unsigned short* p = dst + (size_t)t * stride + hoff + i;
        p[0]  = f2b(x1 * cs - x2 * sn);
        p[64] = f2b(x1 * sn + x2 * cs);
      }
    }
  }
}

// ------------------------------------------------------------------ 128x256 2-phase GEMM
// C = A * B^T fp32 (wo projection). Grid (32,8) = 256 blocks = full chip.
// R5/R6 schedule, HARDENED: vmcnt(2) gate moved from P1-top to before P2's closing
// barrier (gate->barrier->read = cross-wave sound; count unchanged — end-of-P2(T)
// outstanding = [A(T+1) 2, B(T+1) 4, A(T+2) 2] = 8 glds, drain to 2).
__global__ __launch_bounds__(512, 2) void gemm128(const unsigned short* __restrict__ A,
                                                  const unsigned short* __restrict__ B,
                                                  float* __restrict__ Cout) {
  extern __shared__ char smem[];   // 2 x 49152 B
  const int tid = threadIdx.x;
  const int w = tid >> 6, lane = tid & 63;
  const int quad = lane >> 4, l15 = lane & 15;
  const int wm = w >> 2, wn = w & 3;
  const int m0 = blockIdx.x * 128, n0 = blockIdx.y * 256;

  const int fragOff = l15 * 64 + ((quad * 16) ^ ((l15 & 8) << 2));
  char* const aWave = smem;                              // + dbuf*49152
  char* const bWave = smem + 16384 + (wn >> 1) * 16384;

  const int sr = lane >> 2;
  const int sc = ((lane & 3) * 8) ^ ((lane & 32) ? 16 : 0);   // bf16 col, pre-swizzled
  const unsigned short* const Abase = A + (size_t)(m0 + (w >> 1) * 16 + sr) * 2048 + (w & 1) * 32 + sc;
  const unsigned short* const Bbase = B + (size_t)(n0 + (w >> 1) * 16 + sr) * 2048 + (w & 1) * 32 + sc;

#define G_STAGE_A(tt)                                                                    \
  {                                                                                      \
    const int t_ = ((tt) < 32) ? (tt) : 31;                                              \
    char* const d_ = smem + (t_ & 1) * 49152 + w * 1024;                                 \
    glds16(Abase + (size_t)t_ * 64, d_);                                                 \
    glds16(Abase + (64 * 2048) + (size_t)t_ * 64, d_ + 8192);                            \
  }
#define G_STAGE_B(h, tt)                                                                 \
  {                                                                                      \
    const int t_ = ((tt) < 32) ? (tt) : 31;                                              \
    char* const d_ = smem + (t_ & 1) * 49152 + 16384 + (h) * 16384 + w * 1024;           \
    glds16(Bbase + (size_t)(h) * (128 * 2048) + (size_t)t_ * 64, d_);                    \
    glds16(Bbase + (size_t)(h) * (128 * 2048) + (64 * 2048) + (size_t)t_ * 64, d_ + 8192); \
  }
#define G_RD_A(c)                                                                        \
  _Pragma("unroll") for (int mi = 0; mi < 4; ++mi)                                       \
  _Pragma("unroll") for (int kk = 0; kk < 2; ++kk)                                       \
      af[mi][kk] = *(const short8*)(aWave + (c) * 49152 + ((wm * 4 + mi) * 2 + kk) * 1024 + fragOff);
#define G_RD_B(dst, c, NI0)                                                              \
  _Pragma("unroll") for (int ni = 0; ni < 2; ++ni)                                       \
  _Pragma("unroll") for (int kk = 0; kk < 2; ++kk)                                       \
      dst[ni][kk] = *(const short8*)(bWave + (c) * 49152 + (((wn & 1) * 4 + (NI0) + ni) * 2 + kk) * 1024 + fragOff);

  f32x4 acc[4][4];
  const f32x4 fz = {0.f, 0.f, 0.f, 0.f};
#pragma unroll
  for (int i = 0; i < 4; ++i)
#pragma unroll
    for (int j = 0; j < 4; ++j) acc[i][j] = fz;

  short8 af[4][2], blo[2][2], bhi[2][2];

#define G_MFMA(NOFF, BF)                                                         \
  _Pragma("unroll") for (int kk = 0; kk < 2; ++kk)                               \
  _Pragma("unroll") for (int mi = 0; mi < 4; ++mi)                               \
  _Pragma("unroll") for (int ni = 0; ni < 2; ++ni)                               \
      acc[mi][(NOFF) + ni] = __builtin_amdgcn_mfma_f32_16x16x32_bf16(            \
          af[mi][kk], BF[ni][kk], acc[mi][(NOFF) + ni], 0, 0, 0);

  // prologue: A(0)x2, B(0)x4, A(1)x2; gate -> barrier
  G_STAGE_A(0) G_STAGE_B(0, 0) G_STAGE_B(1, 0) G_STAGE_A(1)
  asm volatile("s_waitcnt vmcnt(2)" ::: "memory");
  BARF()

#define G_TILE(c, tt)                                                                \
  /* P1 */ G_RD_A(c) G_RD_B(blo, (c), 0)                                             \
  G_STAGE_B(0, (tt) + 1) G_STAGE_B(1, (tt) + 1)                                      \
  BARF()                                                                             \
  __builtin_amdgcn_s_setprio(1); G_MFMA(0, blo) __builtin_amdgcn_s_setprio(0);       \
  BARF()                                                                             \
  /* P2 */ G_RD_B(bhi, (c), 2)                                                       \
  G_STAGE_A((tt) + 2)                                                                \
  BARF()                                                                             \
  __builtin_amdgcn_s_setprio(1); G_MFMA(2, bhi) __builtin_amdgcn_s_setprio(0);       \
  asm volatile("s_waitcnt vmcnt(2)" ::: "memory");                                   \
  BARF()

#pragma unroll 1
  for (int T = 0; T < 32; T += 2) {
    G_TILE(0, T)
    G_TILE(1, T + 1)
  }
  asm volatile("s_waitcnt vmcnt(0)" ::: "memory");   // drain clamped tail rewrites
#undef G_TILE
#undef G_MFMA
#undef G_RD_A
#undef G_RD_B
#undef G_STAGE_A
#undef G_STAGE_B

  const int colBase = n0 + wn * 64;
#pragma unroll
  for (int mi = 0; mi < 4; ++mi) {
    const int row = m0 + wm * 64 + mi * 16 + quad * 4;
#pragma unroll
    for (int ni = 0; ni < 4; ++ni) {
      const int col = colBase + ni * 16 + l15;
#pragma unroll
      for (int r = 0; r < 4; ++r)
        Cout[(size_t)(row + r) * 2048 + col] = acc[mi][ni][r];
    }
  }
}

// ------------------------------------------------------------ windowed GQA attention
// Block: 8 waves, 64 queries, one kv group. wave w: head g*4+(w&3), query-half w>>2.
__global__ __launch_bounds__(512) void attn_fwd(const unsigned short* __restrict__ qp,
                                                const unsigned short* __restrict__ kp,
                                                const unsigned short* __restrict__ vtg,
                                                unsigned short* __restrict__ op) {
  __shared__ unsigned short Ks[2][4][1024];   // [buf][kb][key*32+d']
  __shared__ unsigned short Vt[2][4096];      // [buf][d*32+key]
  const int tid = threadIdx.x;
  const int w = tid >> 6, lane = tid & 63;
  const int quad = lane >> 4, l15 = lane & 15;
  const int t0 = blockIdx.x * 64;
  const int g = blockIdx.y;
  const int h = g * 4 + (w & 3);
  const int t0w = t0 + (w >> 2) * 32;         // this wave's 32-query base
  const f32x4 fzero = {0.f, 0.f, 0.f, 0.f};
  const float scale = 0.088388347648318447f;  // 1/sqrt(128)
  const float NEG_INF = -__builtin_inff();

  short8 qf[4][2];
#pragma unroll
  for (int qt = 0; qt < 2; qt++) {
    const unsigned short* qrow = qp + (size_t)(t0w + qt * 16 + l15) * 2048 + h * 128 + quad * 8;
#pragma unroll
    for (int kb = 0; kb < 4; kb++) qf[kb][qt] = *(const short8*)(qrow + kb * 32);
  }

  f32x4 oacc[8][2];
#pragma unroll
  for (int db = 0; db < 8; db++) { oacc[db][0] = fzero; oacc[db][1] = fzero; }
  float Mrow[2] = {-1.0e30f, -1.0e30f}, Lrow[2] = {0.f, 0.f};

  const int s_begin = (t0 >= 512) ? (t0 - 512) : 0;
  const int nch = ((t0 + 63 - s_begin) >> 5) + 1;

  const int r4 = lane >> 2, c4 = lane & 3;
#define ATTN_STAGE(s0_, b_)                                                              \
  {                                                                                      \
    const int s0v = (s0_);                                                               \
    if (w < 4) {                                                                         \
      _Pragma("unroll")                                                                  \
      for (int p = 0; p < 2; p++)                                                        \
        glds16(kp + (size_t)(s0v + p * 16 + r4) * 512 + g * 128 + w * 32 + c4 * 8,       \
               &Ks[b_][w][p * 512]);                                                     \
    } else {                                                                             \
      const int wv = w - 4;                                                              \
      _Pragma("unroll")                                                                  \
      for (int p = 0; p < 2; p++)                                                        \
        glds16(vtg + (size_t)(g * 128 + wv * 32 + p * 16 + r4) * 4096 + s0v + c4 * 8,    \
               &Vt[b_][wv * 1024 + p * 512]);                                            \
    }                                                                                    \
  }

  ATTN_STAGE(s_begin, 0);

  for (int c = 0; c < nch; ++c) {
    const int s0 = s_begin + c * 32;
    const int b = c & 1;
    __syncthreads();                       // drain glds for chunk c (uniform)
    if (c + 1 < nch) ATTN_STAGE(s_begin + (c + 1) * 32, (c + 1) & 1);

    if (s0 + 31 >= t0w - 512 && s0 <= t0w + 31) {
      // ---- S^T = K * Q^T, permuted key rows
      f32x4 sacc[2][2];
      sacc[0][0] = fzero; sacc[0][1] = fzero; sacc[1][0] = fzero; sacc[1][1] = fzero;
      const int permBase = ((l15 >> 2) << 3) + (l15 & 3);   // + 4*kt
#pragma unroll
      for (int kb = 0; kb < 4; kb++) {
        short8 af0 = *(const short8*)&Ks[b][kb][(permBase + 0) * 32 + quad * 8];
        short8 af1 = *(const short8*)&Ks[b][kb][(permBase + 4) * 32 + quad * 8];
        sacc[0][0] = __builtin_amdgcn_mfma_f32_16x16x32_bf16(af0, qf[kb][0], sacc[0][0], 0, 0, 0);
        sacc[0][1] = __builtin_amdgcn_mfma_f32_16x16x32_bf16(af0, qf[kb][1], sacc[0][1], 0, 0, 0);
        sacc[1][0] = __builtin_amdgcn_mfma_f32_16x16x32_bf16(af1, qf[kb][0], sacc[1][0], 0, 0, 0);
        sacc[1][1] = __builtin_amdgcn_mfma_f32_16x16x32_bf16(af1, qf[kb][1], sacc[1][1], 0, 0, 0);
      }

      // ---- masked online softmax; key for (kt,r) = s0 + quad*8 + kt*4 + r
      short8 pb[2];
      float alpha[2];
#pragma unroll
      for (int qt = 0; qt < 2; qt++) {
        const int tq = t0w + qt * 16 + l15;
        float vals[8];
        float cmax = NEG_INF;
#pragma unroll
        for (int kt = 0; kt < 2; kt++)
#pragma unroll
          for (int r = 0; r < 4; r++) {
            const int s = s0 + quad * 8 + kt * 4 + r;
            const bool ok = (unsigned)(tq - s) <= 512u;
            const float v = ok ? sacc[kt][qt][r] * scale : NEG_INF;
            vals[kt * 4 + r] = v;
            cmax = fmaxf(cmax, v);
          }
        cmax = fmaxf(cmax, __shfl_xor(cmax, 16));
        cmax = fmaxf(cmax, __shfl_xor(cmax, 32));
        const float Mnew = fmaxf(Mrow[qt], cmax);
        alpha[qt] = __expf(Mrow[qt] - Mnew);
        Mrow[qt] = Mnew;
        float csum = 0.f;
#pragma unroll
        for (int j = 0; j < 8; j++) {
          const float p = __expf(vals[j] - Mnew);
          csum += p;
          pb[qt][j] = (short)f2b(p);
        }
        csum += __shfl_xor(csum, 16);
        csum += __shfl_xor(csum, 32);
        Lrow[qt] = Lrow[qt] * alpha[qt] + csum;
      }

      // ---- O^T += V^T * P^T
#pragma unroll
      for (int db = 0; db < 8; db++) {
        short8 vf = *(const short8*)&Vt[b][(db * 16 + l15) * 32 + quad * 8];
#pragma unroll
        for (int qt = 0; qt < 2; qt++) {
          oacc[db][qt][0] *= alpha[qt]; oacc[db][qt][1] *= alpha[qt];
          oacc[db][qt][2] *= alpha[qt]; oacc[db][qt][3] *= alpha[qt];
          oacc[db][qt] = __builtin_amdgcn_mfma_f32_16x16x32_bf16(vf, pb[qt], oacc[db][qt], 0, 0, 0);
        }
      }
    }
  }
#undef ATTN_STAGE

#pragma unroll
  for (int qt = 0; qt < 2; qt++) {
    const float invL = 1.f / Lrow[qt];
    unsigned short* orow = op + (size_t)(t0w + qt * 16 + l15) * 2048 + h * 128;
#pragma unroll
    for (int db = 0; db < 8; db++) {
      u16x4 o;
#pragma unroll
      for (int r = 0; r < 4; r++) o[r] = f2b(oacc[db][qt][r] * invL);
      *(u16x4*)(orow + db * 16 + quad * 4) = o;
    }
  }
}

// ---------------------------------------------------------------- launch
extern "C" void kernel_launch(void* const* d_in, const int* in_sizes, int n_in,
                              void* d_out, int out_size, void* d_ws, size_t ws_size,
                              hipStream_t stream) {
  const float* x  = (const float*)d_in[0];
  const float* wq = (const float*)d_in[1];
  const float* wk = (const float*)d_in[2];
  const float* wv = (const float*)d_in[3];
  const float* wo = (const float*)d_in[4];
  float* out = (float*)d_out;
  char* ws = (char*)d_ws;

  // workspace map (~63 MB); attnb aliases xb (dead after qkv GEMM)
  unsigned short* xb    = (unsigned short*)(ws + 0);           // 16,777,216 B
  unsigned short* wqkv  = (unsigned short*)(ws + 16777216);    // 12,582,912 B
  unsigned short* wob   = (unsigned short*)(ws + 29360128);    //  8,388,608 B
  unsigned short* qb    = (unsigned short*)(ws + 37748736);    // 16,777,216 B
  unsigned short* kbuf  = (unsigned short*)(ws + 54525952);    //  4,194,304 B
  unsigned short* vtg   = (unsigned short*)(ws + 58720256);    //  4,194,304 B
  unsigned short* attnb = xb;

  static bool attr_done = false;
  if (!attr_done) {   // allow big dynamic LDS (host-side, not stream-ordered)
    hipFuncSetAttribute(reinterpret_cast<const void*>(gemm_t128),
                        hipFuncAttributeMaxDynamicSharedMemorySize, 65536);
    hipFuncSetAttribute(reinterpret_cast<const void*>(gemm128),
                        hipFuncAttributeMaxDynamicSharedMemorySize, 98304);
    attr_done = true;
  }

  cast_all<<<18432, 256, 0, stream>>>(x, wq, wk, wv, wo, (unsigned short*)ws);

  // qkv proj + fused RoPE + fused V-transpose: 128^2 tiles, 768 blocks, 2-resident
  gemm_t128<<<dim3(32, 24), 512, 65536, stream>>>(xb, wqkv, 1, qb, kbuf, vtg, nullptr);

  attn_fwd<<<dim3(64, 4), 512, 0, stream>>>(qb, kbuf, vtg, attnb);

  // out = attn @ wo^T  (4096 x 2048, K=2048), fp32 out — 128x256 tiles, 256 blocks
  gemm128<<<dim3(32, 8), 512, 98304, stream>>>(attnb, wob, out);
}